// Round 12
// baseline (218.704 us; speedup 1.0000x reference)
//
#include <hip/hip_runtime.h>

typedef unsigned short u16;
typedef __attribute__((ext_vector_type(8))) short bf16x8;
typedef __attribute__((ext_vector_type(4))) float f32x4;

#define MFMA16(A,B,C) __builtin_amdgcn_mfma_f32_16x16x32_bf16(A,B,C,0,0,0)

#define B_ 4
#define C_ 256
#define N_ 2304
#define HEADS_ 8
#define DH_ 64
#define INNER_ 512
#define SCALE_LOG2E 14.426950408889634f   // 10 * log2(e); also the fixed max bias

__device__ __forceinline__ u16 f2bf(float f) {
    union { float f; unsigned int u; } v; v.f = f;
    unsigned int r = v.u + 0x7fffu + ((v.u >> 16) & 1u);
    return (u16)(r >> 16);
}
// pack two floats to bf16x2 (round-half-up) in 3 VALU ops
__device__ __forceinline__ unsigned int pk2(float a, float b) {
    union { float f; unsigned int u; } va, vb; va.f = a; vb.f = b;
    return __builtin_amdgcn_perm(vb.u + 0x8000u, va.u + 0x8000u, 0x07060302u);
}

// ---------------- Kernel P: fused prep (transpose x + convert weights) ----------------
__global__ __launch_bounds__(256) void k_prep(const float* __restrict__ x,
                                              u16* __restrict__ xT,
                                              const float* __restrict__ w_qkv,
                                              u16* __restrict__ wqb,
                                              const float* __restrict__ w_out,
                                              u16* __restrict__ wob) {
    __shared__ float tile[64][65];
    int idx = blockIdx.x;
    int t = threadIdx.x;
    if (idx < 576) {
        int b = idx / 144, rem = idx % 144;
        int n0 = (rem >> 2) * 64, c0 = (rem & 3) * 64;
        const float* xb = x + (size_t)b * C_ * N_;
        u16* xTb = xT + (size_t)b * N_ * C_;
        int r = t >> 4;
        int q4 = (t & 15) * 4;
#pragma unroll
        for (int pass = 0; pass < 4; ++pass) {
            int c = r + pass * 16;
            float4 v = *(const float4*)(xb + (size_t)(c0 + c) * N_ + n0 + q4);
            tile[c][q4+0] = v.x; tile[c][q4+1] = v.y; tile[c][q4+2] = v.z; tile[c][q4+3] = v.w;
        }
        __syncthreads();
#pragma unroll
        for (int pass = 0; pass < 4; ++pass) {
            int n = r + pass * 16;
            ushort4 o;
            o.x = f2bf(tile[q4+0][n]); o.y = f2bf(tile[q4+1][n]);
            o.z = f2bf(tile[q4+2][n]); o.w = f2bf(tile[q4+3][n]);
            *(ushort4*)(xTb + (size_t)(n0 + n) * C_ + c0 + q4) = o;
        }
    } else if (idx < 960) {
        int i = (idx - 576) * 256 + t;
        float4 v = ((const float4*)w_qkv)[i];
        ushort4 o;
        o.x = f2bf(v.x); o.y = f2bf(v.y); o.z = f2bf(v.z); o.w = f2bf(v.w);
        ((ushort4*)wqb)[i] = o;
    } else {
        int i = (idx - 960) * 256 + t;
        float4 v = ((const float4*)w_out)[i];
        ushort4 o;
        o.x = f2bf(v.x); o.y = f2bf(v.y); o.z = f2bf(v.z); o.w = f2bf(v.w);
        ((ushort4*)wob)[i] = o;
    }
}

// ---------------- Kernel 1: QKV GEMM (LDS-staged) + l2norm(q,k) ----------------
__global__ __launch_bounds__(256) void k_qkv(const u16* __restrict__ w_qkv,
                                             const u16* __restrict__ xT,
                                             u16* __restrict__ Qn,
                                             u16* __restrict__ Kn,
                                             u16* __restrict__ Vt) {
    __shared__ __align__(16) u16 Wt[64][264];
    __shared__ __align__(16) u16 Xt[64][264];
    int mt = blockIdx.x, nt = blockIdx.y, b = blockIdx.z;
    int tid = threadIdx.x;
    int wv = tid >> 6, lane = tid & 63;
    int col = lane & 15, quad = lane >> 4;
    int o0 = mt * 64;
    const u16* wtile = w_qkv + (size_t)o0 * C_;
    const u16* xtile = xT + ((size_t)b * N_ + nt*64) * C_;
#pragma unroll
    for (int p = 0; p < 8; ++p) {
        int c = p * 256 + tid;
        int row = c >> 5, seg = c & 31;
        *(uint4*)(&Wt[row][seg*8]) = *(const uint4*)(wtile + (size_t)row * C_ + seg*8);
        *(uint4*)(&Xt[row][seg*8]) = *(const uint4*)(xtile + (size_t)row * C_ + seg*8);
    }
    __syncthreads();
    f32x4 z = {0.f, 0.f, 0.f, 0.f};
    f32x4 acc[4]; acc[0]=z; acc[1]=z; acc[2]=z; acc[3]=z;
#pragma unroll
    for (int ks = 0; ks < 8; ++ks) {
        bf16x8 bfrag = *(const bf16x8*)(&Xt[wv*16 + col][ks*32 + quad*8]);
#pragma unroll
        for (int mb = 0; mb < 4; ++mb) {
            bf16x8 afrag = *(const bf16x8*)(&Wt[mb*16 + col][ks*32 + quad*8]);
            acc[mb] = MFMA16(afrag, bfrag, acc[mb]);
        }
    }
    int n = nt * 64 + wv * 16 + col;
    int which = mt >> 3, h = mt & 7;
    if (which < 2) {
        float s = 0.f;
#pragma unroll
        for (int mb = 0; mb < 4; ++mb)
#pragma unroll
            for (int r = 0; r < 4; ++r) s += acc[mb][r] * acc[mb][r];
        s += __shfl_xor(s, 16);
        s += __shfl_xor(s, 32);
        float inv = 1.f / fmaxf(sqrtf(s), 1e-12f);
        u16* dst = (which == 0 ? Qn : Kn) + (((size_t)b * HEADS_ + h) * N_ + n) * DH_;
#pragma unroll
        for (int mb = 0; mb < 4; ++mb) {
            ushort4 o;
            o.x = f2bf(acc[mb][0] * inv); o.y = f2bf(acc[mb][1] * inv);
            o.z = f2bf(acc[mb][2] * inv); o.w = f2bf(acc[mb][3] * inv);
            *(ushort4*)(dst + mb*16 + quad*4) = o;
        }
    } else {
        u16* dst = Vt + ((size_t)b * HEADS_ + h) * (size_t)DH_ * N_;
#pragma unroll
        for (int mb = 0; mb < 4; ++mb)
#pragma unroll
            for (int r = 0; r < 4; ++r)
                dst[(size_t)(mb*16 + quad*4 + r) * N_ + n] = f2bf(acc[mb][r]);
    }
}

// ---------------- Kernel 2: flash attention (S^T/O^T, fixed-max, 32 q/wave) ----------
// 2-wave blocks, 64-q tile. Each wave computes TWO 16-q subtiles so every K/V
// LDS fragment read is reused twice (per-q LDS read traffic -45% vs R11).
// Prefetch: 8 named uint4 scalars, unconditional clamped index (no-spill pattern).
__global__ __launch_bounds__(128) void k_attn(const u16* __restrict__ Qn,
                                              const u16* __restrict__ Kn,
                                              const u16* __restrict__ Vt,
                                              u16* __restrict__ AO) {
    __shared__ __align__(16) u16 Kt[64][72];        // k-rows x d (pad 8)
    __shared__ __align__(16) u16 Vtl[64][72];       // d-rows x k (pad 8)
    __shared__ __align__(16) u16 plds[2][32][72];   // per-wave P^T: rows 0-15 subA, 16-31 subB
    int head_lin = blockIdx.x & 31;                 // head -> XCD pinning
    int qt = blockIdx.x >> 5;                       // 0..35
    int b = head_lin >> 3, h = head_lin & 7;
    int tid = threadIdx.x;                          // 0..127
    int wv = tid >> 6, lane = tid & 63;
    int col = lane & 15, quad = lane >> 4;
    size_t head = (size_t)b * HEADS_ + h;
    const u16* Qh = Qn + head * (size_t)N_ * DH_;
    const u16* Kh = Kn + head * (size_t)N_ * DH_;
    const u16* Vh = Vt + head * (size_t)DH_ * N_;
    int q0 = qt * 64 + wv * 32;
    bf16x8 qfA0 = *(const bf16x8*)(Qh + (size_t)(q0 + col) * DH_ + quad*8);
    bf16x8 qfA1 = *(const bf16x8*)(Qh + (size_t)(q0 + col) * DH_ + 32 + quad*8);
    bf16x8 qfB0 = *(const bf16x8*)(Qh + (size_t)(q0 + 16 + col) * DH_ + quad*8);
    bf16x8 qfB1 = *(const bf16x8*)(Qh + (size_t)(q0 + 16 + col) * DH_ + 32 + quad*8);
    f32x4 z = {0.f, 0.f, 0.f, 0.f};
    f32x4 OA[4], OB[4];
#pragma unroll
    for (int i = 0; i < 4; ++i) { OA[i] = z; OB[i] = z; }
    float lA = 0.f, lB = 0.f;
    int srow = tid >> 3, sseg = tid & 7;            // staging coords (p-stride 16 rows)
    const u16* ksrc0 = Kh + (size_t)tid * 8;        // dense 16B/lane
    const u16* vsrc0 = Vh + (size_t)srow * N_ + sseg * 8;

    uint4 k0 = *(const uint4*)(ksrc0);
    uint4 k1 = *(const uint4*)(ksrc0 + 1024);
    uint4 k2 = *(const uint4*)(ksrc0 + 2048);
    uint4 k3 = *(const uint4*)(ksrc0 + 3072);
    uint4 v0 = *(const uint4*)(vsrc0);
    uint4 v1 = *(const uint4*)(vsrc0 + (size_t)16 * N_);
    uint4 v2 = *(const uint4*)(vsrc0 + (size_t)32 * N_);
    uint4 v3 = *(const uint4*)(vsrc0 + (size_t)48 * N_);

    for (int kt = 0; kt < N_/64; ++kt) {            // 36 iterations
        // commit prefetched tile to LDS
        *(uint4*)(&Kt[srow][sseg*8])      = k0;
        *(uint4*)(&Kt[16 + srow][sseg*8]) = k1;
        *(uint4*)(&Kt[32 + srow][sseg*8]) = k2;
        *(uint4*)(&Kt[48 + srow][sseg*8]) = k3;
        *(uint4*)(&Vtl[srow][sseg*8])      = v0;
        *(uint4*)(&Vtl[16 + srow][sseg*8]) = v1;
        *(uint4*)(&Vtl[32 + srow][sseg*8]) = v2;
        *(uint4*)(&Vtl[48 + srow][sseg*8]) = v3;
        __syncthreads();   // tile visible
        // unconditional clamped prefetch of tile kt+1
        int ktn = kt + 1 < N_/64 ? kt + 1 : kt;
        k0 = *(const uint4*)(ksrc0 + (size_t)ktn * 4096);
        k1 = *(const uint4*)(ksrc0 + (size_t)ktn * 4096 + 1024);
        k2 = *(const uint4*)(ksrc0 + (size_t)ktn * 4096 + 2048);
        k3 = *(const uint4*)(ksrc0 + (size_t)ktn * 4096 + 3072);
        v0 = *(const uint4*)(vsrc0 + ktn * 64);
        v1 = *(const uint4*)(vsrc0 + (size_t)16 * N_ + ktn * 64);
        v2 = *(const uint4*)(vsrc0 + (size_t)32 * N_ + ktn * 64);
        v3 = *(const uint4*)(vsrc0 + (size_t)48 * N_ + ktn * 64);
        // S^T (both q-subtiles share each K fragment) + fixed-max softmax + pack
        float rsA = 0.f, rsB = 0.f;
#pragma unroll
        for (int nb = 0; nb < 4; ++nb) {
            bf16x8 kf0 = *(const bf16x8*)(&Kt[nb*16 + col][quad*8]);
            bf16x8 kf1 = *(const bf16x8*)(&Kt[nb*16 + col][32 + quad*8]);
            f32x4 a = MFMA16(kf0, qfA0, z);
            a = MFMA16(kf1, qfA1, a);
            f32x4 c = MFMA16(kf0, qfB0, z);
            c = MFMA16(kf1, qfB1, c);
            float a0 = exp2f(fmaf(a[0], SCALE_LOG2E, -SCALE_LOG2E));
            float a1 = exp2f(fmaf(a[1], SCALE_LOG2E, -SCALE_LOG2E));
            float a2 = exp2f(fmaf(a[2], SCALE_LOG2E, -SCALE_LOG2E));
            float a3 = exp2f(fmaf(a[3], SCALE_LOG2E, -SCALE_LOG2E));
            float c0 = exp2f(fmaf(c[0], SCALE_LOG2E, -SCALE_LOG2E));
            float c1 = exp2f(fmaf(c[1], SCALE_LOG2E, -SCALE_LOG2E));
            float c2 = exp2f(fmaf(c[2], SCALE_LOG2E, -SCALE_LOG2E));
            float c3 = exp2f(fmaf(c[3], SCALE_LOG2E, -SCALE_LOG2E));
            rsA += (a0 + a1) + (a2 + a3);
            rsB += (c0 + c1) + (c2 + c3);
            uint2 wA, wB;
            wA.x = pk2(a0, a1); wA.y = pk2(a2, a3);
            wB.x = pk2(c0, c1); wB.y = pk2(c2, c3);
            *(uint2*)(&plds[wv][col][nb*16 + quad*4]) = wA;
            *(uint2*)(&plds[wv][16 + col][nb*16 + quad*4]) = wB;
        }
        lA += rsA; lB += rsB;
        __asm__ volatile("" ::: "memory");   // wave-private plds ordering
        // O^T += V^T P^T (V fragment shared by both subtiles)
#pragma unroll
        for (int ks = 0; ks < 2; ++ks) {
            bf16x8 pfA = *(const bf16x8*)(&plds[wv][col][ks*32 + quad*8]);
            bf16x8 pfB = *(const bf16x8*)(&plds[wv][16 + col][ks*32 + quad*8]);
#pragma unroll
            for (int nb = 0; nb < 4; ++nb) {
                bf16x8 vf = *(const bf16x8*)(&Vtl[nb*16 + col][ks*32 + quad*8]);
                OA[nb] = MFMA16(vf, pfA, OA[nb]);
                OB[nb] = MFMA16(vf, pfB, OB[nb]);
            }
        }
        __asm__ volatile("" ::: "memory");   // WAR vs next iter's plds writes
        __syncthreads();   // all tile reads done before next iter's commits
    }
    lA += __shfl_xor(lA, 16); lA += __shfl_xor(lA, 32);
    lB += __shfl_xor(lB, 16); lB += __shfl_xor(lB, 32);
    float linvA = 1.f / lA, linvB = 1.f / lB;
    u16* dstA = AO + ((size_t)b * N_ + q0 + col) * INNER_ + h * DH_;
    u16* dstB = AO + ((size_t)b * N_ + q0 + 16 + col) * INNER_ + h * DH_;
#pragma unroll
    for (int nb = 0; nb < 4; ++nb) {
        uint2 wA, wB;
        wA.x = pk2(OA[nb][0] * linvA, OA[nb][1] * linvA);
        wA.y = pk2(OA[nb][2] * linvA, OA[nb][3] * linvA);
        wB.x = pk2(OB[nb][0] * linvB, OB[nb][1] * linvB);
        wB.y = pk2(OB[nb][2] * linvB, OB[nb][3] * linvB);
        *(uint2*)(dstA + nb*16 + quad*4) = wA;
        *(uint2*)(dstB + nb*16 + quad*4) = wB;
    }
}

// ---------------- Kernel 3: output projection (LDS-staged) + bias ----------------
__global__ __launch_bounds__(256) void k_proj(const u16* __restrict__ w_out,
                                              const float* __restrict__ b_out,
                                              const u16* __restrict__ AO,
                                              float* __restrict__ out) {
    __shared__ __align__(16) u16 Wt[64][264];
    __shared__ __align__(16) u16 At[64][264];
    int mt = blockIdx.x, nt = blockIdx.y, b = blockIdx.z;
    int tid = threadIdx.x;
    int wv = tid >> 6, lane = tid & 63;
    int col = lane & 15, quad = lane >> 4;
    int o0b = mt * 64;
    const u16* wtile = w_out + (size_t)o0b * INNER_;
    const u16* atile = AO + ((size_t)b * N_ + nt*64) * INNER_;
    f32x4 z = {0.f, 0.f, 0.f, 0.f};
    f32x4 acc[4]; acc[0]=z; acc[1]=z; acc[2]=z; acc[3]=z;
#pragma unroll
    for (int half = 0; half < 2; ++half) {
        if (half) __syncthreads();
#pragma unroll
        for (int p = 0; p < 8; ++p) {
            int c = p * 256 + tid;
            int row = c >> 5, seg = c & 31;
            *(uint4*)(&Wt[row][seg*8]) =
                *(const uint4*)(wtile + (size_t)row * INNER_ + half*256 + seg*8);
            *(uint4*)(&At[row][seg*8]) =
                *(const uint4*)(atile + (size_t)row * INNER_ + half*256 + seg*8);
        }
        __syncthreads();
#pragma unroll
        for (int ks = 0; ks < 8; ++ks) {
            bf16x8 af = *(const bf16x8*)(&Wt[wv*16 + col][ks*32 + quad*8]);
#pragma unroll
            for (int nb = 0; nb < 4; ++nb) {
                bf16x8 bfv = *(const bf16x8*)(&At[nb*16 + col][ks*32 + quad*8]);
                acc[nb] = MFMA16(af, bfv, acc[nb]);
            }
        }
    }
    int o0 = o0b + wv * 16;
    float bias[4];
#pragma unroll
    for (int r = 0; r < 4; ++r) bias[r] = b_out[o0 + quad*4 + r];
    float* dst = out + ((size_t)b * C_ + o0) * N_ + nt*64;
#pragma unroll
    for (int nb = 0; nb < 4; ++nb)
#pragma unroll
        for (int r = 0; r < 4; ++r)
            dst[(size_t)(quad*4 + r) * N_ + nb*16 + col] = acc[nb][r] + bias[r];
}

// ---------------- launch ----------------
extern "C" void kernel_launch(void* const* d_in, const int* in_sizes, int n_in,
                              void* d_out, int out_size, void* d_ws, size_t ws_size,
                              hipStream_t stream) {
    const float* x     = (const float*)d_in[0];
    const float* w_qkv = (const float*)d_in[1];
    const float* w_out = (const float*)d_in[2];
    const float* b_out = (const float*)d_in[3];
    float* out = (float*)d_out;

    char* ws = (char*)d_ws;
    u16* xT  = (u16*)(ws);
    u16* Qn  = (u16*)(ws + 4718592);
    u16* Kn  = (u16*)(ws + 14155776);
    u16* Vt  = (u16*)(ws + 23592960);
    u16* AO  = (u16*)(ws + 33030144);
    u16* wqb = (u16*)(ws + 42467328);
    u16* wob = (u16*)(ws + 43253760);

    hipLaunchKernelGGL(k_prep, dim3(1088), dim3(256), 0, stream, x, xT, w_qkv, wqb, w_out, wob);
    hipLaunchKernelGGL(k_qkv,  dim3(24, N_/64, B_), dim3(256), 0, stream, wqb, xT, Qn, Kn, Vt);
    hipLaunchKernelGGL(k_attn, dim3((N_/64) * 32), dim3(128), 0, stream, Qn, Kn, Vt, AO);
    hipLaunchKernelGGL(k_proj, dim3(C_/64, N_/64, B_), dim3(256), 0, stream, wob, b_out, AO, out);
}

// Round 13
// 205.220 us; speedup vs baseline: 1.0657x; 1.0657x over previous
//
#include <hip/hip_runtime.h>

typedef unsigned short u16;
typedef __attribute__((ext_vector_type(8))) short bf16x8;
typedef __attribute__((ext_vector_type(4))) float f32x4;

#define MFMA16(A,B,C) __builtin_amdgcn_mfma_f32_16x16x32_bf16(A,B,C,0,0,0)

#define B_ 4
#define C_ 256
#define N_ 2304
#define HEADS_ 8
#define DH_ 64
#define INNER_ 512
#define SCALE_LOG2E 14.426950408889634f   // 10 * log2(e); also the fixed max bias

__device__ __forceinline__ u16 f2bf(float f) {
    union { float f; unsigned int u; } v; v.f = f;
    unsigned int r = v.u + 0x7fffu + ((v.u >> 16) & 1u);
    return (u16)(r >> 16);
}
// pack two floats to bf16x2 (round-half-up) in 3 VALU ops
__device__ __forceinline__ unsigned int pk2(float a, float b) {
    union { float f; unsigned int u; } va, vb; va.f = a; vb.f = b;
    return __builtin_amdgcn_perm(vb.u + 0x8000u, va.u + 0x8000u, 0x07060302u);
}

// ---------------- Kernel P: fused prep (transpose x + convert weights) ----------------
__global__ __launch_bounds__(256) void k_prep(const float* __restrict__ x,
                                              u16* __restrict__ xT,
                                              const float* __restrict__ w_qkv,
                                              u16* __restrict__ wqb,
                                              const float* __restrict__ w_out,
                                              u16* __restrict__ wob) {
    __shared__ float tile[64][65];
    int idx = blockIdx.x;
    int t = threadIdx.x;
    if (idx < 576) {
        int b = idx / 144, rem = idx % 144;
        int n0 = (rem >> 2) * 64, c0 = (rem & 3) * 64;
        const float* xb = x + (size_t)b * C_ * N_;
        u16* xTb = xT + (size_t)b * N_ * C_;
        int r = t >> 4;
        int q4 = (t & 15) * 4;
#pragma unroll
        for (int pass = 0; pass < 4; ++pass) {
            int c = r + pass * 16;
            float4 v = *(const float4*)(xb + (size_t)(c0 + c) * N_ + n0 + q4);
            tile[c][q4+0] = v.x; tile[c][q4+1] = v.y; tile[c][q4+2] = v.z; tile[c][q4+3] = v.w;
        }
        __syncthreads();
#pragma unroll
        for (int pass = 0; pass < 4; ++pass) {
            int n = r + pass * 16;
            ushort4 o;
            o.x = f2bf(tile[q4+0][n]); o.y = f2bf(tile[q4+1][n]);
            o.z = f2bf(tile[q4+2][n]); o.w = f2bf(tile[q4+3][n]);
            *(ushort4*)(xTb + (size_t)(n0 + n) * C_ + c0 + q4) = o;
        }
    } else if (idx < 960) {
        int i = (idx - 576) * 256 + t;
        float4 v = ((const float4*)w_qkv)[i];
        ushort4 o;
        o.x = f2bf(v.x); o.y = f2bf(v.y); o.z = f2bf(v.z); o.w = f2bf(v.w);
        ((ushort4*)wqb)[i] = o;
    } else {
        int i = (idx - 960) * 256 + t;
        float4 v = ((const float4*)w_out)[i];
        ushort4 o;
        o.x = f2bf(v.x); o.y = f2bf(v.y); o.z = f2bf(v.z); o.w = f2bf(v.w);
        ((ushort4*)wob)[i] = o;
    }
}

// ---------------- Kernel 1: QKV GEMM (LDS-staged) + l2norm(q,k) ----------------
__global__ __launch_bounds__(256) void k_qkv(const u16* __restrict__ w_qkv,
                                             const u16* __restrict__ xT,
                                             u16* __restrict__ Qn,
                                             u16* __restrict__ Kn,
                                             u16* __restrict__ Vt) {
    __shared__ __align__(16) u16 Wt[64][264];
    __shared__ __align__(16) u16 Xt[64][264];
    int mt = blockIdx.x, nt = blockIdx.y, b = blockIdx.z;
    int tid = threadIdx.x;
    int wv = tid >> 6, lane = tid & 63;
    int col = lane & 15, quad = lane >> 4;
    int o0 = mt * 64;
    const u16* wtile = w_qkv + (size_t)o0 * C_;
    const u16* xtile = xT + ((size_t)b * N_ + nt*64) * C_;
#pragma unroll
    for (int p = 0; p < 8; ++p) {
        int c = p * 256 + tid;
        int row = c >> 5, seg = c & 31;
        *(uint4*)(&Wt[row][seg*8]) = *(const uint4*)(wtile + (size_t)row * C_ + seg*8);
        *(uint4*)(&Xt[row][seg*8]) = *(const uint4*)(xtile + (size_t)row * C_ + seg*8);
    }
    __syncthreads();
    f32x4 z = {0.f, 0.f, 0.f, 0.f};
    f32x4 acc[4]; acc[0]=z; acc[1]=z; acc[2]=z; acc[3]=z;
#pragma unroll
    for (int ks = 0; ks < 8; ++ks) {
        bf16x8 bfrag = *(const bf16x8*)(&Xt[wv*16 + col][ks*32 + quad*8]);
#pragma unroll
        for (int mb = 0; mb < 4; ++mb) {
            bf16x8 afrag = *(const bf16x8*)(&Wt[mb*16 + col][ks*32 + quad*8]);
            acc[mb] = MFMA16(afrag, bfrag, acc[mb]);
        }
    }
    int n = nt * 64 + wv * 16 + col;
    int which = mt >> 3, h = mt & 7;
    if (which < 2) {
        float s = 0.f;
#pragma unroll
        for (int mb = 0; mb < 4; ++mb)
#pragma unroll
            for (int r = 0; r < 4; ++r) s += acc[mb][r] * acc[mb][r];
        s += __shfl_xor(s, 16);
        s += __shfl_xor(s, 32);
        float inv = 1.f / fmaxf(sqrtf(s), 1e-12f);
        u16* dst = (which == 0 ? Qn : Kn) + (((size_t)b * HEADS_ + h) * N_ + n) * DH_;
#pragma unroll
        for (int mb = 0; mb < 4; ++mb) {
            ushort4 o;
            o.x = f2bf(acc[mb][0] * inv); o.y = f2bf(acc[mb][1] * inv);
            o.z = f2bf(acc[mb][2] * inv); o.w = f2bf(acc[mb][3] * inv);
            *(ushort4*)(dst + mb*16 + quad*4) = o;
        }
    } else {
        u16* dst = Vt + ((size_t)b * HEADS_ + h) * (size_t)DH_ * N_;
#pragma unroll
        for (int mb = 0; mb < 4; ++mb)
#pragma unroll
            for (int r = 0; r < 4; ++r)
                dst[(size_t)(mb*16 + quad*4 + r) * N_ + n] = f2bf(acc[mb][r]);
    }
}

// ---------------- Kernel 2: flash attention (S^T/O^T, fixed-max, 32 q/wave, 4-wave) --
// 4-wave 256-thr blocks, 128-q tile (wave wv owns q [qt*128+wv*32, +32)).
// Each wave computes TWO 16-q subtiles: every K/V LDS fragment read reused 2x.
// Prefetch: 4 named uint4 scalars/thread, unconditional clamped index (no-spill).
__global__ __launch_bounds__(256) void k_attn(const u16* __restrict__ Qn,
                                              const u16* __restrict__ Kn,
                                              const u16* __restrict__ Vt,
                                              u16* __restrict__ AO) {
    __shared__ __align__(16) u16 Kt[64][72];        // k-rows x d (pad 8)
    __shared__ __align__(16) u16 Vtl[64][72];       // d-rows x k (pad 8)
    __shared__ __align__(16) u16 plds[4][32][72];   // per-wave P^T: rows 0-15 subA, 16-31 subB
    int head_lin = blockIdx.x & 31;                 // head -> XCD pinning
    int qt = blockIdx.x >> 5;                       // 0..17 (128-q tiles)
    int b = head_lin >> 3, h = head_lin & 7;
    int tid = threadIdx.x;                          // 0..255
    int wv = tid >> 6, lane = tid & 63;
    int col = lane & 15, quad = lane >> 4;
    size_t head = (size_t)b * HEADS_ + h;
    const u16* Qh = Qn + head * (size_t)N_ * DH_;
    const u16* Kh = Kn + head * (size_t)N_ * DH_;
    const u16* Vh = Vt + head * (size_t)DH_ * N_;
    int q0 = qt * 128 + wv * 32;
    bf16x8 qfA0 = *(const bf16x8*)(Qh + (size_t)(q0 + col) * DH_ + quad*8);
    bf16x8 qfA1 = *(const bf16x8*)(Qh + (size_t)(q0 + col) * DH_ + 32 + quad*8);
    bf16x8 qfB0 = *(const bf16x8*)(Qh + (size_t)(q0 + 16 + col) * DH_ + quad*8);
    bf16x8 qfB1 = *(const bf16x8*)(Qh + (size_t)(q0 + 16 + col) * DH_ + 32 + quad*8);
    f32x4 z = {0.f, 0.f, 0.f, 0.f};
    f32x4 OA[4], OB[4];
#pragma unroll
    for (int i = 0; i < 4; ++i) { OA[i] = z; OB[i] = z; }
    float lA = 0.f, lB = 0.f;
    int srow = tid >> 3, sseg = tid & 7;            // staging coords (rows 0..31)
    const u16* ksrc0 = Kh + (size_t)tid * 8;        // rows 0..31, dense 16B/lane
    const u16* vsrc0 = Vh + (size_t)srow * N_ + sseg * 8;

    uint4 k0 = *(const uint4*)(ksrc0);
    uint4 k1 = *(const uint4*)(ksrc0 + 2048);
    uint4 v0 = *(const uint4*)(vsrc0);
    uint4 v1 = *(const uint4*)(vsrc0 + (size_t)32 * N_);

    for (int kt = 0; kt < N_/64; ++kt) {            // 36 iterations
        // commit prefetched tile to LDS
        *(uint4*)(&Kt[srow][sseg*8])      = k0;
        *(uint4*)(&Kt[32 + srow][sseg*8]) = k1;
        *(uint4*)(&Vtl[srow][sseg*8])      = v0;
        *(uint4*)(&Vtl[32 + srow][sseg*8]) = v1;
        __syncthreads();   // tile visible
        // unconditional clamped prefetch of tile kt+1
        int ktn = kt + 1 < N_/64 ? kt + 1 : kt;
        k0 = *(const uint4*)(ksrc0 + (size_t)ktn * 4096);
        k1 = *(const uint4*)(ksrc0 + (size_t)ktn * 4096 + 2048);
        v0 = *(const uint4*)(vsrc0 + ktn * 64);
        v1 = *(const uint4*)(vsrc0 + (size_t)32 * N_ + ktn * 64);
        // S^T (both q-subtiles share each K fragment) + fixed-max softmax + pack
        float rsA = 0.f, rsB = 0.f;
#pragma unroll
        for (int nb = 0; nb < 4; ++nb) {
            bf16x8 kf0 = *(const bf16x8*)(&Kt[nb*16 + col][quad*8]);
            bf16x8 kf1 = *(const bf16x8*)(&Kt[nb*16 + col][32 + quad*8]);
            f32x4 a = MFMA16(kf0, qfA0, z);
            a = MFMA16(kf1, qfA1, a);
            f32x4 c = MFMA16(kf0, qfB0, z);
            c = MFMA16(kf1, qfB1, c);
            float a0 = exp2f(fmaf(a[0], SCALE_LOG2E, -SCALE_LOG2E));
            float a1 = exp2f(fmaf(a[1], SCALE_LOG2E, -SCALE_LOG2E));
            float a2 = exp2f(fmaf(a[2], SCALE_LOG2E, -SCALE_LOG2E));
            float a3 = exp2f(fmaf(a[3], SCALE_LOG2E, -SCALE_LOG2E));
            float c0 = exp2f(fmaf(c[0], SCALE_LOG2E, -SCALE_LOG2E));
            float c1 = exp2f(fmaf(c[1], SCALE_LOG2E, -SCALE_LOG2E));
            float c2 = exp2f(fmaf(c[2], SCALE_LOG2E, -SCALE_LOG2E));
            float c3 = exp2f(fmaf(c[3], SCALE_LOG2E, -SCALE_LOG2E));
            rsA += (a0 + a1) + (a2 + a3);
            rsB += (c0 + c1) + (c2 + c3);
            uint2 wA, wB;
            wA.x = pk2(a0, a1); wA.y = pk2(a2, a3);
            wB.x = pk2(c0, c1); wB.y = pk2(c2, c3);
            *(uint2*)(&plds[wv][col][nb*16 + quad*4]) = wA;
            *(uint2*)(&plds[wv][16 + col][nb*16 + quad*4]) = wB;
        }
        lA += rsA; lB += rsB;
        __asm__ volatile("" ::: "memory");   // wave-private plds ordering
        // O^T += V^T P^T (V fragment shared by both subtiles)
#pragma unroll
        for (int ks = 0; ks < 2; ++ks) {
            bf16x8 pfA = *(const bf16x8*)(&plds[wv][col][ks*32 + quad*8]);
            bf16x8 pfB = *(const bf16x8*)(&plds[wv][16 + col][ks*32 + quad*8]);
#pragma unroll
            for (int nb = 0; nb < 4; ++nb) {
                bf16x8 vf = *(const bf16x8*)(&Vtl[nb*16 + col][ks*32 + quad*8]);
                OA[nb] = MFMA16(vf, pfA, OA[nb]);
                OB[nb] = MFMA16(vf, pfB, OB[nb]);
            }
        }
        __asm__ volatile("" ::: "memory");   // WAR vs next iter's plds writes
        __syncthreads();   // all tile reads done before next iter's commits
    }
    lA += __shfl_xor(lA, 16); lA += __shfl_xor(lA, 32);
    lB += __shfl_xor(lB, 16); lB += __shfl_xor(lB, 32);
    float linvA = 1.f / lA, linvB = 1.f / lB;
    u16* dstA = AO + ((size_t)b * N_ + q0 + col) * INNER_ + h * DH_;
    u16* dstB = AO + ((size_t)b * N_ + q0 + 16 + col) * INNER_ + h * DH_;
#pragma unroll
    for (int nb = 0; nb < 4; ++nb) {
        uint2 wA, wB;
        wA.x = pk2(OA[nb][0] * linvA, OA[nb][1] * linvA);
        wA.y = pk2(OA[nb][2] * linvA, OA[nb][3] * linvA);
        wB.x = pk2(OB[nb][0] * linvB, OB[nb][1] * linvB);
        wB.y = pk2(OB[nb][2] * linvB, OB[nb][3] * linvB);
        *(uint2*)(dstA + nb*16 + quad*4) = wA;
        *(uint2*)(dstB + nb*16 + quad*4) = wB;
    }
}

// ---------------- Kernel 3: output projection (LDS-staged) + bias ----------------
__global__ __launch_bounds__(256) void k_proj(const u16* __restrict__ w_out,
                                              const float* __restrict__ b_out,
                                              const u16* __restrict__ AO,
                                              float* __restrict__ out) {
    __shared__ __align__(16) u16 Wt[64][264];
    __shared__ __align__(16) u16 At[64][264];
    int mt = blockIdx.x, nt = blockIdx.y, b = blockIdx.z;
    int tid = threadIdx.x;
    int wv = tid >> 6, lane = tid & 63;
    int col = lane & 15, quad = lane >> 4;
    int o0b = mt * 64;
    const u16* wtile = w_out + (size_t)o0b * INNER_;
    const u16* atile = AO + ((size_t)b * N_ + nt*64) * INNER_;
    f32x4 z = {0.f, 0.f, 0.f, 0.f};
    f32x4 acc[4]; acc[0]=z; acc[1]=z; acc[2]=z; acc[3]=z;
#pragma unroll
    for (int half = 0; half < 2; ++half) {
        if (half) __syncthreads();
#pragma unroll
        for (int p = 0; p < 8; ++p) {
            int c = p * 256 + tid;
            int row = c >> 5, seg = c & 31;
            *(uint4*)(&Wt[row][seg*8]) =
                *(const uint4*)(wtile + (size_t)row * INNER_ + half*256 + seg*8);
            *(uint4*)(&At[row][seg*8]) =
                *(const uint4*)(atile + (size_t)row * INNER_ + half*256 + seg*8);
        }
        __syncthreads();
#pragma unroll
        for (int ks = 0; ks < 8; ++ks) {
            bf16x8 af = *(const bf16x8*)(&Wt[wv*16 + col][ks*32 + quad*8]);
#pragma unroll
            for (int nb = 0; nb < 4; ++nb) {
                bf16x8 bfv = *(const bf16x8*)(&At[nb*16 + col][ks*32 + quad*8]);
                acc[nb] = MFMA16(af, bfv, acc[nb]);
            }
        }
    }
    int o0 = o0b + wv * 16;
    float bias[4];
#pragma unroll
    for (int r = 0; r < 4; ++r) bias[r] = b_out[o0 + quad*4 + r];
    float* dst = out + ((size_t)b * C_ + o0) * N_ + nt*64;
#pragma unroll
    for (int nb = 0; nb < 4; ++nb)
#pragma unroll
        for (int r = 0; r < 4; ++r)
            dst[(size_t)(quad*4 + r) * N_ + nb*16 + col] = acc[nb][r] + bias[r];
}

// ---------------- launch ----------------
extern "C" void kernel_launch(void* const* d_in, const int* in_sizes, int n_in,
                              void* d_out, int out_size, void* d_ws, size_t ws_size,
                              hipStream_t stream) {
    const float* x     = (const float*)d_in[0];
    const float* w_qkv = (const float*)d_in[1];
    const float* w_out = (const float*)d_in[2];
    const float* b_out = (const float*)d_in[3];
    float* out = (float*)d_out;

    char* ws = (char*)d_ws;
    u16* xT  = (u16*)(ws);
    u16* Qn  = (u16*)(ws + 4718592);
    u16* Kn  = (u16*)(ws + 14155776);
    u16* Vt  = (u16*)(ws + 23592960);
    u16* AO  = (u16*)(ws + 33030144);
    u16* wqb = (u16*)(ws + 42467328);
    u16* wob = (u16*)(ws + 43253760);

    hipLaunchKernelGGL(k_prep, dim3(1088), dim3(256), 0, stream, x, xT, w_qkv, wqb, w_out, wob);
    hipLaunchKernelGGL(k_qkv,  dim3(24, N_/64, B_), dim3(256), 0, stream, wqb, xT, Qn, Kn, Vt);
    hipLaunchKernelGGL(k_attn, dim3((N_/128) * 32), dim3(256), 0, stream, Qn, Kn, Vt, AO);
    hipLaunchKernelGGL(k_proj, dim3(C_/64, N_/64, B_), dim3(256), 0, stream, wob, b_out, AO, out);
}

// Round 14
// 196.279 us; speedup vs baseline: 1.1143x; 1.0456x over previous
//
#include <hip/hip_runtime.h>

typedef unsigned short u16;
typedef __attribute__((ext_vector_type(8))) short bf16x8;
typedef __attribute__((ext_vector_type(4))) float f32x4;

#define MFMA16(A,B,C) __builtin_amdgcn_mfma_f32_16x16x32_bf16(A,B,C,0,0,0)

#define B_ 4
#define C_ 256
#define N_ 2304
#define HEADS_ 8
#define DH_ 64
#define INNER_ 512
#define SCALE_LOG2E 14.426950408889634f   // 10 * log2(e); also the fixed max bias

__device__ __forceinline__ u16 f2bf(float f) {
    union { float f; unsigned int u; } v; v.f = f;
    unsigned int r = v.u + 0x7fffu + ((v.u >> 16) & 1u);
    return (u16)(r >> 16);
}
// pack two floats to bf16x2 (round-half-up) in 3 VALU ops
__device__ __forceinline__ unsigned int pk2(float a, float b) {
    union { float f; unsigned int u; } va, vb; va.f = a; vb.f = b;
    return __builtin_amdgcn_perm(vb.u + 0x8000u, va.u + 0x8000u, 0x07060302u);
}

// ---------------- Kernel P: fused prep (transpose x + convert weights) ----------------
__global__ __launch_bounds__(256) void k_prep(const float* __restrict__ x,
                                              u16* __restrict__ xT,
                                              const float* __restrict__ w_qkv,
                                              u16* __restrict__ wqb,
                                              const float* __restrict__ w_out,
                                              u16* __restrict__ wob) {
    __shared__ float tile[64][65];
    int idx = blockIdx.x;
    int t = threadIdx.x;
    if (idx < 576) {
        int b = idx / 144, rem = idx % 144;
        int n0 = (rem >> 2) * 64, c0 = (rem & 3) * 64;
        const float* xb = x + (size_t)b * C_ * N_;
        u16* xTb = xT + (size_t)b * N_ * C_;
        int r = t >> 4;
        int q4 = (t & 15) * 4;
#pragma unroll
        for (int pass = 0; pass < 4; ++pass) {
            int c = r + pass * 16;
            float4 v = *(const float4*)(xb + (size_t)(c0 + c) * N_ + n0 + q4);
            tile[c][q4+0] = v.x; tile[c][q4+1] = v.y; tile[c][q4+2] = v.z; tile[c][q4+3] = v.w;
        }
        __syncthreads();
#pragma unroll
        for (int pass = 0; pass < 4; ++pass) {
            int n = r + pass * 16;
            ushort4 o;
            o.x = f2bf(tile[q4+0][n]); o.y = f2bf(tile[q4+1][n]);
            o.z = f2bf(tile[q4+2][n]); o.w = f2bf(tile[q4+3][n]);
            *(ushort4*)(xTb + (size_t)(n0 + n) * C_ + c0 + q4) = o;
        }
    } else if (idx < 960) {
        int i = (idx - 576) * 256 + t;
        float4 v = ((const float4*)w_qkv)[i];
        ushort4 o;
        o.x = f2bf(v.x); o.y = f2bf(v.y); o.z = f2bf(v.z); o.w = f2bf(v.w);
        ((ushort4*)wqb)[i] = o;
    } else {
        int i = (idx - 960) * 256 + t;
        float4 v = ((const float4*)w_out)[i];
        ushort4 o;
        o.x = f2bf(v.x); o.y = f2bf(v.y); o.z = f2bf(v.z); o.w = f2bf(v.w);
        ((ushort4*)wob)[i] = o;
    }
}

// ---------------- Kernel 1: QKV GEMM (LDS-staged) + l2norm(q,k) ----------------
__global__ __launch_bounds__(256) void k_qkv(const u16* __restrict__ w_qkv,
                                             const u16* __restrict__ xT,
                                             u16* __restrict__ Qn,
                                             u16* __restrict__ Kn,
                                             u16* __restrict__ Vt) {
    __shared__ __align__(16) u16 Wt[64][264];
    __shared__ __align__(16) u16 Xt[64][264];
    int mt = blockIdx.x, nt = blockIdx.y, b = blockIdx.z;
    int tid = threadIdx.x;
    int wv = tid >> 6, lane = tid & 63;
    int col = lane & 15, quad = lane >> 4;
    int o0 = mt * 64;
    const u16* wtile = w_qkv + (size_t)o0 * C_;
    const u16* xtile = xT + ((size_t)b * N_ + nt*64) * C_;
#pragma unroll
    for (int p = 0; p < 8; ++p) {
        int c = p * 256 + tid;
        int row = c >> 5, seg = c & 31;
        *(uint4*)(&Wt[row][seg*8]) = *(const uint4*)(wtile + (size_t)row * C_ + seg*8);
        *(uint4*)(&Xt[row][seg*8]) = *(const uint4*)(xtile + (size_t)row * C_ + seg*8);
    }
    __syncthreads();
    f32x4 z = {0.f, 0.f, 0.f, 0.f};
    f32x4 acc[4]; acc[0]=z; acc[1]=z; acc[2]=z; acc[3]=z;
#pragma unroll
    for (int ks = 0; ks < 8; ++ks) {
        bf16x8 bfrag = *(const bf16x8*)(&Xt[wv*16 + col][ks*32 + quad*8]);
#pragma unroll
        for (int mb = 0; mb < 4; ++mb) {
            bf16x8 afrag = *(const bf16x8*)(&Wt[mb*16 + col][ks*32 + quad*8]);
            acc[mb] = MFMA16(afrag, bfrag, acc[mb]);
        }
    }
    int n = nt * 64 + wv * 16 + col;
    int which = mt >> 3, h = mt & 7;
    if (which < 2) {
        float s = 0.f;
#pragma unroll
        for (int mb = 0; mb < 4; ++mb)
#pragma unroll
            for (int r = 0; r < 4; ++r) s += acc[mb][r] * acc[mb][r];
        s += __shfl_xor(s, 16);
        s += __shfl_xor(s, 32);
        float inv = 1.f / fmaxf(sqrtf(s), 1e-12f);
        u16* dst = (which == 0 ? Qn : Kn) + (((size_t)b * HEADS_ + h) * N_ + n) * DH_;
#pragma unroll
        for (int mb = 0; mb < 4; ++mb) {
            ushort4 o;
            o.x = f2bf(acc[mb][0] * inv); o.y = f2bf(acc[mb][1] * inv);
            o.z = f2bf(acc[mb][2] * inv); o.w = f2bf(acc[mb][3] * inv);
            *(ushort4*)(dst + mb*16 + quad*4) = o;
        }
    } else {
        u16* dst = Vt + ((size_t)b * HEADS_ + h) * (size_t)DH_ * N_;
#pragma unroll
        for (int mb = 0; mb < 4; ++mb)
#pragma unroll
            for (int r = 0; r < 4; ++r)
                dst[(size_t)(mb*16 + quad*4 + r) * N_ + n] = f2bf(acc[mb][r]);
    }
}

// ---------------- Kernel 2a: flash attention, 2-way K-split, f32 partials ----------
// blockIdx.x = khalf*576 + qt*32 + head_lin. Each block: 128-q tile, 1152 keys.
// Fixed-max softmax => partials combine linearly: O=(O0+O1)/(l0+l1) in k_comb.
__global__ __launch_bounds__(256) void k_attn_split(const u16* __restrict__ Qn,
                                                    const u16* __restrict__ Kn,
                                                    const u16* __restrict__ Vt,
                                                    float* __restrict__ Op,
                                                    float* __restrict__ lp) {
    __shared__ __align__(16) u16 Kt[64][72];
    __shared__ __align__(16) u16 Vtl[64][72];
    __shared__ __align__(16) u16 plds[4][32][72];
    int head_lin = blockIdx.x & 31;                 // head -> XCD pinning
    int rest = blockIdx.x >> 5;                     // 0..35
    int qt = rest % 18;
    int khalf = rest / 18;
    int b = head_lin >> 3, h = head_lin & 7;
    int tid = threadIdx.x;
    int wv = tid >> 6, lane = tid & 63;
    int col = lane & 15, quad = lane >> 4;
    size_t head = (size_t)b * HEADS_ + h;
    const u16* Qh = Qn + head * (size_t)N_ * DH_;
    const u16* Kh = Kn + head * (size_t)N_ * DH_ + (size_t)khalf * 1152 * DH_;
    const u16* Vh = Vt + head * (size_t)DH_ * N_;
    int q0 = qt * 128 + wv * 32;
    bf16x8 qfA0 = *(const bf16x8*)(Qh + (size_t)(q0 + col) * DH_ + quad*8);
    bf16x8 qfA1 = *(const bf16x8*)(Qh + (size_t)(q0 + col) * DH_ + 32 + quad*8);
    bf16x8 qfB0 = *(const bf16x8*)(Qh + (size_t)(q0 + 16 + col) * DH_ + quad*8);
    bf16x8 qfB1 = *(const bf16x8*)(Qh + (size_t)(q0 + 16 + col) * DH_ + 32 + quad*8);
    f32x4 z = {0.f, 0.f, 0.f, 0.f};
    f32x4 OA[4], OB[4];
#pragma unroll
    for (int i = 0; i < 4; ++i) { OA[i] = z; OB[i] = z; }
    float lA = 0.f, lB = 0.f;
    int srow = tid >> 3, sseg = tid & 7;
    const u16* ksrc0 = Kh + (size_t)tid * 8;
    const u16* vsrc0 = Vh + (size_t)srow * N_ + khalf * 1152 + sseg * 8;

    uint4 k0 = *(const uint4*)(ksrc0);
    uint4 k1 = *(const uint4*)(ksrc0 + 2048);
    uint4 v0 = *(const uint4*)(vsrc0);
    uint4 v1 = *(const uint4*)(vsrc0 + (size_t)32 * N_);

    for (int kt = 0; kt < 18; ++kt) {
        *(uint4*)(&Kt[srow][sseg*8])      = k0;
        *(uint4*)(&Kt[32 + srow][sseg*8]) = k1;
        *(uint4*)(&Vtl[srow][sseg*8])      = v0;
        *(uint4*)(&Vtl[32 + srow][sseg*8]) = v1;
        __syncthreads();
        int ktn = kt + 1 < 18 ? kt + 1 : kt;
        k0 = *(const uint4*)(ksrc0 + (size_t)ktn * 4096);
        k1 = *(const uint4*)(ksrc0 + (size_t)ktn * 4096 + 2048);
        v0 = *(const uint4*)(vsrc0 + ktn * 64);
        v1 = *(const uint4*)(vsrc0 + (size_t)32 * N_ + ktn * 64);
        float rsA = 0.f, rsB = 0.f;
#pragma unroll
        for (int nb = 0; nb < 4; ++nb) {
            bf16x8 kf0 = *(const bf16x8*)(&Kt[nb*16 + col][quad*8]);
            bf16x8 kf1 = *(const bf16x8*)(&Kt[nb*16 + col][32 + quad*8]);
            f32x4 a = MFMA16(kf0, qfA0, z);
            a = MFMA16(kf1, qfA1, a);
            f32x4 c = MFMA16(kf0, qfB0, z);
            c = MFMA16(kf1, qfB1, c);
            float a0 = exp2f(fmaf(a[0], SCALE_LOG2E, -SCALE_LOG2E));
            float a1 = exp2f(fmaf(a[1], SCALE_LOG2E, -SCALE_LOG2E));
            float a2 = exp2f(fmaf(a[2], SCALE_LOG2E, -SCALE_LOG2E));
            float a3 = exp2f(fmaf(a[3], SCALE_LOG2E, -SCALE_LOG2E));
            float c0 = exp2f(fmaf(c[0], SCALE_LOG2E, -SCALE_LOG2E));
            float c1 = exp2f(fmaf(c[1], SCALE_LOG2E, -SCALE_LOG2E));
            float c2 = exp2f(fmaf(c[2], SCALE_LOG2E, -SCALE_LOG2E));
            float c3 = exp2f(fmaf(c[3], SCALE_LOG2E, -SCALE_LOG2E));
            rsA += (a0 + a1) + (a2 + a3);
            rsB += (c0 + c1) + (c2 + c3);
            uint2 wA, wB;
            wA.x = pk2(a0, a1); wA.y = pk2(a2, a3);
            wB.x = pk2(c0, c1); wB.y = pk2(c2, c3);
            *(uint2*)(&plds[wv][col][nb*16 + quad*4]) = wA;
            *(uint2*)(&plds[wv][16 + col][nb*16 + quad*4]) = wB;
        }
        lA += rsA; lB += rsB;
        __asm__ volatile("" ::: "memory");
#pragma unroll
        for (int ks = 0; ks < 2; ++ks) {
            bf16x8 pfA = *(const bf16x8*)(&plds[wv][col][ks*32 + quad*8]);
            bf16x8 pfB = *(const bf16x8*)(&plds[wv][16 + col][ks*32 + quad*8]);
#pragma unroll
            for (int nb = 0; nb < 4; ++nb) {
                bf16x8 vf = *(const bf16x8*)(&Vtl[nb*16 + col][ks*32 + quad*8]);
                OA[nb] = MFMA16(vf, pfA, OA[nb]);
                OB[nb] = MFMA16(vf, pfB, OB[nb]);
            }
        }
        __asm__ volatile("" ::: "memory");
        __syncthreads();
    }
    lA += __shfl_xor(lA, 16); lA += __shfl_xor(lA, 32);
    lB += __shfl_xor(lB, 16); lB += __shfl_xor(lB, 32);
    // unnormalized f32 partials
    float* dstA = Op + (((size_t)khalf * B_ + b) * N_ + q0 + col) * INNER_ + h * DH_;
    float* dstB = dstA + (size_t)16 * INNER_;
#pragma unroll
    for (int nb = 0; nb < 4; ++nb) {
        *(f32x4*)(dstA + nb*16 + quad*4) = OA[nb];
        *(f32x4*)(dstB + nb*16 + quad*4) = OB[nb];
    }
    if (quad == 0) {
        size_t lbase = (((size_t)khalf * B_ + b) * HEADS_ + h) * N_;
        lp[lbase + q0 + col] = lA;
        lp[lbase + q0 + 16 + col] = lB;
    }
}

// ---------------- Kernel 2c: combine partials -> AO bf16 ----------------
__global__ __launch_bounds__(256) void k_comb(const float* __restrict__ Op,
                                              const float* __restrict__ lp,
                                              u16* __restrict__ AO) {
    int g = blockIdx.x * 256 + threadIdx.x;       // < 1,179,648 float4s per half
    int b = g / 294912;
    int rem = g % 294912;
    int n = rem >> 7;
    int i4 = rem & 127;
    int h = i4 >> 4;
    float4 a = ((const float4*)Op)[g];
    float4 c = ((const float4*)Op)[g + 1179648];
    float l = lp[((size_t)b * HEADS_ + h) * N_ + n] +
              lp[(((size_t)B_ + b) * HEADS_ + h) * N_ + n];
    float inv = 1.f / l;
    ushort4 o;
    o.x = f2bf((a.x + c.x) * inv);
    o.y = f2bf((a.y + c.y) * inv);
    o.z = f2bf((a.z + c.z) * inv);
    o.w = f2bf((a.w + c.w) * inv);
    ((ushort4*)AO)[g] = o;
}

// ---------------- Kernel 2b: fallback single-pass attention (R13) ----------------
__global__ __launch_bounds__(256) void k_attn(const u16* __restrict__ Qn,
                                              const u16* __restrict__ Kn,
                                              const u16* __restrict__ Vt,
                                              u16* __restrict__ AO) {
    __shared__ __align__(16) u16 Kt[64][72];
    __shared__ __align__(16) u16 Vtl[64][72];
    __shared__ __align__(16) u16 plds[4][32][72];
    int head_lin = blockIdx.x & 31;
    int qt = blockIdx.x >> 5;
    int b = head_lin >> 3, h = head_lin & 7;
    int tid = threadIdx.x;
    int wv = tid >> 6, lane = tid & 63;
    int col = lane & 15, quad = lane >> 4;
    size_t head = (size_t)b * HEADS_ + h;
    const u16* Qh = Qn + head * (size_t)N_ * DH_;
    const u16* Kh = Kn + head * (size_t)N_ * DH_;
    const u16* Vh = Vt + head * (size_t)DH_ * N_;
    int q0 = qt * 128 + wv * 32;
    bf16x8 qfA0 = *(const bf16x8*)(Qh + (size_t)(q0 + col) * DH_ + quad*8);
    bf16x8 qfA1 = *(const bf16x8*)(Qh + (size_t)(q0 + col) * DH_ + 32 + quad*8);
    bf16x8 qfB0 = *(const bf16x8*)(Qh + (size_t)(q0 + 16 + col) * DH_ + quad*8);
    bf16x8 qfB1 = *(const bf16x8*)(Qh + (size_t)(q0 + 16 + col) * DH_ + 32 + quad*8);
    f32x4 z = {0.f, 0.f, 0.f, 0.f};
    f32x4 OA[4], OB[4];
#pragma unroll
    for (int i = 0; i < 4; ++i) { OA[i] = z; OB[i] = z; }
    float lA = 0.f, lB = 0.f;
    int srow = tid >> 3, sseg = tid & 7;
    const u16* ksrc0 = Kh + (size_t)tid * 8;
    const u16* vsrc0 = Vh + (size_t)srow * N_ + sseg * 8;

    uint4 k0 = *(const uint4*)(ksrc0);
    uint4 k1 = *(const uint4*)(ksrc0 + 2048);
    uint4 v0 = *(const uint4*)(vsrc0);
    uint4 v1 = *(const uint4*)(vsrc0 + (size_t)32 * N_);

    for (int kt = 0; kt < N_/64; ++kt) {
        *(uint4*)(&Kt[srow][sseg*8])      = k0;
        *(uint4*)(&Kt[32 + srow][sseg*8]) = k1;
        *(uint4*)(&Vtl[srow][sseg*8])      = v0;
        *(uint4*)(&Vtl[32 + srow][sseg*8]) = v1;
        __syncthreads();
        int ktn = kt + 1 < N_/64 ? kt + 1 : kt;
        k0 = *(const uint4*)(ksrc0 + (size_t)ktn * 4096);
        k1 = *(const uint4*)(ksrc0 + (size_t)ktn * 4096 + 2048);
        v0 = *(const uint4*)(vsrc0 + ktn * 64);
        v1 = *(const uint4*)(vsrc0 + (size_t)32 * N_ + ktn * 64);
        float rsA = 0.f, rsB = 0.f;
#pragma unroll
        for (int nb = 0; nb < 4; ++nb) {
            bf16x8 kf0 = *(const bf16x8*)(&Kt[nb*16 + col][quad*8]);
            bf16x8 kf1 = *(const bf16x8*)(&Kt[nb*16 + col][32 + quad*8]);
            f32x4 a = MFMA16(kf0, qfA0, z);
            a = MFMA16(kf1, qfA1, a);
            f32x4 c = MFMA16(kf0, qfB0, z);
            c = MFMA16(kf1, qfB1, c);
            float a0 = exp2f(fmaf(a[0], SCALE_LOG2E, -SCALE_LOG2E));
            float a1 = exp2f(fmaf(a[1], SCALE_LOG2E, -SCALE_LOG2E));
            float a2 = exp2f(fmaf(a[2], SCALE_LOG2E, -SCALE_LOG2E));
            float a3 = exp2f(fmaf(a[3], SCALE_LOG2E, -SCALE_LOG2E));
            float c0 = exp2f(fmaf(c[0], SCALE_LOG2E, -SCALE_LOG2E));
            float c1 = exp2f(fmaf(c[1], SCALE_LOG2E, -SCALE_LOG2E));
            float c2 = exp2f(fmaf(c[2], SCALE_LOG2E, -SCALE_LOG2E));
            float c3 = exp2f(fmaf(c[3], SCALE_LOG2E, -SCALE_LOG2E));
            rsA += (a0 + a1) + (a2 + a3);
            rsB += (c0 + c1) + (c2 + c3);
            uint2 wA, wB;
            wA.x = pk2(a0, a1); wA.y = pk2(a2, a3);
            wB.x = pk2(c0, c1); wB.y = pk2(c2, c3);
            *(uint2*)(&plds[wv][col][nb*16 + quad*4]) = wA;
            *(uint2*)(&plds[wv][16 + col][nb*16 + quad*4]) = wB;
        }
        lA += rsA; lB += rsB;
        __asm__ volatile("" ::: "memory");
#pragma unroll
        for (int ks = 0; ks < 2; ++ks) {
            bf16x8 pfA = *(const bf16x8*)(&plds[wv][col][ks*32 + quad*8]);
            bf16x8 pfB = *(const bf16x8*)(&plds[wv][16 + col][ks*32 + quad*8]);
#pragma unroll
            for (int nb = 0; nb < 4; ++nb) {
                bf16x8 vf = *(const bf16x8*)(&Vtl[nb*16 + col][ks*32 + quad*8]);
                OA[nb] = MFMA16(vf, pfA, OA[nb]);
                OB[nb] = MFMA16(vf, pfB, OB[nb]);
            }
        }
        __asm__ volatile("" ::: "memory");
        __syncthreads();
    }
    lA += __shfl_xor(lA, 16); lA += __shfl_xor(lA, 32);
    lB += __shfl_xor(lB, 16); lB += __shfl_xor(lB, 32);
    float linvA = 1.f / lA, linvB = 1.f / lB;
    u16* dstA = AO + ((size_t)b * N_ + q0 + col) * INNER_ + h * DH_;
    u16* dstB = AO + ((size_t)b * N_ + q0 + 16 + col) * INNER_ + h * DH_;
#pragma unroll
    for (int nb = 0; nb < 4; ++nb) {
        uint2 wA, wB;
        wA.x = pk2(OA[nb][0] * linvA, OA[nb][1] * linvA);
        wA.y = pk2(OA[nb][2] * linvA, OA[nb][3] * linvA);
        wB.x = pk2(OB[nb][0] * linvB, OB[nb][1] * linvB);
        wB.y = pk2(OB[nb][2] * linvB, OB[nb][3] * linvB);
        *(uint2*)(dstA + nb*16 + quad*4) = wA;
        *(uint2*)(dstB + nb*16 + quad*4) = wB;
    }
}

// ---------------- Kernel 3: output projection (LDS-staged) + bias ----------------
__global__ __launch_bounds__(256) void k_proj(const u16* __restrict__ w_out,
                                              const float* __restrict__ b_out,
                                              const u16* __restrict__ AO,
                                              float* __restrict__ out) {
    __shared__ __align__(16) u16 Wt[64][264];
    __shared__ __align__(16) u16 At[64][264];
    int mt = blockIdx.x, nt = blockIdx.y, b = blockIdx.z;
    int tid = threadIdx.x;
    int wv = tid >> 6, lane = tid & 63;
    int col = lane & 15, quad = lane >> 4;
    int o0b = mt * 64;
    const u16* wtile = w_out + (size_t)o0b * INNER_;
    const u16* atile = AO + ((size_t)b * N_ + nt*64) * INNER_;
    f32x4 z = {0.f, 0.f, 0.f, 0.f};
    f32x4 acc[4]; acc[0]=z; acc[1]=z; acc[2]=z; acc[3]=z;
#pragma unroll
    for (int half = 0; half < 2; ++half) {
        if (half) __syncthreads();
#pragma unroll
        for (int p = 0; p < 8; ++p) {
            int c = p * 256 + tid;
            int row = c >> 5, seg = c & 31;
            *(uint4*)(&Wt[row][seg*8]) =
                *(const uint4*)(wtile + (size_t)row * INNER_ + half*256 + seg*8);
            *(uint4*)(&At[row][seg*8]) =
                *(const uint4*)(atile + (size_t)row * INNER_ + half*256 + seg*8);
        }
        __syncthreads();
#pragma unroll
        for (int ks = 0; ks < 8; ++ks) {
            bf16x8 af = *(const bf16x8*)(&Wt[wv*16 + col][ks*32 + quad*8]);
#pragma unroll
            for (int nb = 0; nb < 4; ++nb) {
                bf16x8 bfv = *(const bf16x8*)(&At[nb*16 + col][ks*32 + quad*8]);
                acc[nb] = MFMA16(af, bfv, acc[nb]);
            }
        }
    }
    int o0 = o0b + wv * 16;
    float bias[4];
#pragma unroll
    for (int r = 0; r < 4; ++r) bias[r] = b_out[o0 + quad*4 + r];
    float* dst = out + ((size_t)b * C_ + o0) * N_ + nt*64;
#pragma unroll
    for (int nb = 0; nb < 4; ++nb)
#pragma unroll
        for (int r = 0; r < 4; ++r)
            dst[(size_t)(quad*4 + r) * N_ + nb*16 + col] = acc[nb][r] + bias[r];
}

// ---------------- launch ----------------
extern "C" void kernel_launch(void* const* d_in, const int* in_sizes, int n_in,
                              void* d_out, int out_size, void* d_ws, size_t ws_size,
                              hipStream_t stream) {
    const float* x     = (const float*)d_in[0];
    const float* w_qkv = (const float*)d_in[1];
    const float* w_out = (const float*)d_in[2];
    const float* b_out = (const float*)d_in[3];
    float* out = (float*)d_out;

    char* ws = (char*)d_ws;
    u16* xT  = (u16*)(ws);
    u16* Qn  = (u16*)(ws + 4718592);
    u16* Kn  = (u16*)(ws + 14155776);
    u16* Vt  = (u16*)(ws + 23592960);
    u16* AO  = (u16*)(ws + 33030144);
    u16* wqb = (u16*)(ws + 42467328);
    u16* wob = (u16*)(ws + 43253760);
    float* Op = (float*)(ws + 43515904);   // 2 x 18,874,368 B f32 partials
    float* lp = (float*)(ws + 81264640);   // 2 x 294,912 B f32 row sums
    const size_t need = 81854464;

    hipLaunchKernelGGL(k_prep, dim3(1088), dim3(256), 0, stream, x, xT, w_qkv, wqb, w_out, wob);
    hipLaunchKernelGGL(k_qkv,  dim3(24, N_/64, B_), dim3(256), 0, stream, wqb, xT, Qn, Kn, Vt);
    if (ws_size >= need) {
        hipLaunchKernelGGL(k_attn_split, dim3(1152), dim3(256), 0, stream, Qn, Kn, Vt, Op, lp);
        hipLaunchKernelGGL(k_comb, dim3(4608), dim3(256), 0, stream, Op, lp, AO);
    } else {
        hipLaunchKernelGGL(k_attn, dim3((N_/128) * 32), dim3(256), 0, stream, Qn, Kn, Vt, AO);
    }
    hipLaunchKernelGGL(k_proj, dim3(C_/64, N_/64, B_), dim3(256), 0, stream, wob, b_out, AO, out);
}

// Round 15
// 196.199 us; speedup vs baseline: 1.1147x; 1.0004x over previous
//
#include <hip/hip_runtime.h>

typedef unsigned short u16;
typedef __attribute__((ext_vector_type(8))) short bf16x8;
typedef __attribute__((ext_vector_type(4))) float f32x4;

#define MFMA16(A,B,C) __builtin_amdgcn_mfma_f32_16x16x32_bf16(A,B,C,0,0,0)

#define B_ 4
#define C_ 256
#define N_ 2304
#define HEADS_ 8
#define DH_ 64
#define INNER_ 512
#define SCALE_LOG2E 14.426950408889634f   // 10 * log2(e); also the fixed max bias

__device__ __forceinline__ u16 f2bf(float f) {
    union { float f; unsigned int u; } v; v.f = f;
    unsigned int r = v.u + 0x7fffu + ((v.u >> 16) & 1u);
    return (u16)(r >> 16);
}
// pack two floats to bf16x2 (round-half-up) in 3 VALU ops
__device__ __forceinline__ unsigned int pk2(float a, float b) {
    union { float f; unsigned int u; } va, vb; va.f = a; vb.f = b;
    return __builtin_amdgcn_perm(vb.u + 0x8000u, va.u + 0x8000u, 0x07060302u);
}

// ---------------- Kernel P: fused prep (transpose x + convert weights) ----------------
__global__ __launch_bounds__(256) void k_prep(const float* __restrict__ x,
                                              u16* __restrict__ xT,
                                              const float* __restrict__ w_qkv,
                                              u16* __restrict__ wqb,
                                              const float* __restrict__ w_out,
                                              u16* __restrict__ wob) {
    __shared__ float tile[64][65];
    int idx = blockIdx.x;
    int t = threadIdx.x;
    if (idx < 576) {
        int b = idx / 144, rem = idx % 144;
        int n0 = (rem >> 2) * 64, c0 = (rem & 3) * 64;
        const float* xb = x + (size_t)b * C_ * N_;
        u16* xTb = xT + (size_t)b * N_ * C_;
        int r = t >> 4;
        int q4 = (t & 15) * 4;
#pragma unroll
        for (int pass = 0; pass < 4; ++pass) {
            int c = r + pass * 16;
            float4 v = *(const float4*)(xb + (size_t)(c0 + c) * N_ + n0 + q4);
            tile[c][q4+0] = v.x; tile[c][q4+1] = v.y; tile[c][q4+2] = v.z; tile[c][q4+3] = v.w;
        }
        __syncthreads();
#pragma unroll
        for (int pass = 0; pass < 4; ++pass) {
            int n = r + pass * 16;
            ushort4 o;
            o.x = f2bf(tile[q4+0][n]); o.y = f2bf(tile[q4+1][n]);
            o.z = f2bf(tile[q4+2][n]); o.w = f2bf(tile[q4+3][n]);
            *(ushort4*)(xTb + (size_t)(n0 + n) * C_ + c0 + q4) = o;
        }
    } else if (idx < 960) {
        int i = (idx - 576) * 256 + t;
        float4 v = ((const float4*)w_qkv)[i];
        ushort4 o;
        o.x = f2bf(v.x); o.y = f2bf(v.y); o.z = f2bf(v.z); o.w = f2bf(v.w);
        ((ushort4*)wqb)[i] = o;
    } else {
        int i = (idx - 960) * 256 + t;
        float4 v = ((const float4*)w_out)[i];
        ushort4 o;
        o.x = f2bf(v.x); o.y = f2bf(v.y); o.z = f2bf(v.z); o.w = f2bf(v.w);
        ((ushort4*)wob)[i] = o;
    }
}

// ---------------- Kernel 1: QKV GEMM (LDS-staged) + l2norm(q,k) ----------------
__global__ __launch_bounds__(256) void k_qkv(const u16* __restrict__ w_qkv,
                                             const u16* __restrict__ xT,
                                             u16* __restrict__ Qn,
                                             u16* __restrict__ Kn,
                                             u16* __restrict__ Vt) {
    __shared__ __align__(16) u16 Wt[64][264];
    __shared__ __align__(16) u16 Xt[64][264];
    int mt = blockIdx.x, nt = blockIdx.y, b = blockIdx.z;
    int tid = threadIdx.x;
    int wv = tid >> 6, lane = tid & 63;
    int col = lane & 15, quad = lane >> 4;
    int o0 = mt * 64;
    const u16* wtile = w_qkv + (size_t)o0 * C_;
    const u16* xtile = xT + ((size_t)b * N_ + nt*64) * C_;
#pragma unroll
    for (int p = 0; p < 8; ++p) {
        int c = p * 256 + tid;
        int row = c >> 5, seg = c & 31;
        *(uint4*)(&Wt[row][seg*8]) = *(const uint4*)(wtile + (size_t)row * C_ + seg*8);
        *(uint4*)(&Xt[row][seg*8]) = *(const uint4*)(xtile + (size_t)row * C_ + seg*8);
    }
    __syncthreads();
    f32x4 z = {0.f, 0.f, 0.f, 0.f};
    f32x4 acc[4]; acc[0]=z; acc[1]=z; acc[2]=z; acc[3]=z;
#pragma unroll
    for (int ks = 0; ks < 8; ++ks) {
        bf16x8 bfrag = *(const bf16x8*)(&Xt[wv*16 + col][ks*32 + quad*8]);
#pragma unroll
        for (int mb = 0; mb < 4; ++mb) {
            bf16x8 afrag = *(const bf16x8*)(&Wt[mb*16 + col][ks*32 + quad*8]);
            acc[mb] = MFMA16(afrag, bfrag, acc[mb]);
        }
    }
    int n = nt * 64 + wv * 16 + col;
    int which = mt >> 3, h = mt & 7;
    if (which < 2) {
        float s = 0.f;
#pragma unroll
        for (int mb = 0; mb < 4; ++mb)
#pragma unroll
            for (int r = 0; r < 4; ++r) s += acc[mb][r] * acc[mb][r];
        s += __shfl_xor(s, 16);
        s += __shfl_xor(s, 32);
        float inv = 1.f / fmaxf(sqrtf(s), 1e-12f);
        u16* dst = (which == 0 ? Qn : Kn) + (((size_t)b * HEADS_ + h) * N_ + n) * DH_;
#pragma unroll
        for (int mb = 0; mb < 4; ++mb) {
            ushort4 o;
            o.x = f2bf(acc[mb][0] * inv); o.y = f2bf(acc[mb][1] * inv);
            o.z = f2bf(acc[mb][2] * inv); o.w = f2bf(acc[mb][3] * inv);
            *(ushort4*)(dst + mb*16 + quad*4) = o;
        }
    } else {
        u16* dst = Vt + ((size_t)b * HEADS_ + h) * (size_t)DH_ * N_;
#pragma unroll
        for (int mb = 0; mb < 4; ++mb)
#pragma unroll
            for (int r = 0; r < 4; ++r)
                dst[(size_t)(mb*16 + quad*4 + r) * N_ + n] = f2bf(acc[mb][r]);
    }
}

// ---------------- Kernel 2a: flash attention, 2-way K-split, 48 q/wave ----------
// blockIdx.x: head_lin = &31, rest>>5 in 0..23: qt = rest%12, khalf = rest/12.
// Grid 768 = exactly 3 blocks/CU. Each wave: THREE 16-q subtiles -> every K/V
// LDS fragment read reused 3x. Fixed-max softmax; f32 partials combined in k_comb.
__global__ __launch_bounds__(256) void k_attn_split(const u16* __restrict__ Qn,
                                                    const u16* __restrict__ Kn,
                                                    const u16* __restrict__ Vt,
                                                    float* __restrict__ Op,
                                                    float* __restrict__ lp) {
    __shared__ __align__(16) u16 Kt[64][72];
    __shared__ __align__(16) u16 Vtl[64][72];
    __shared__ __align__(16) u16 plds[4][48][72];
    int head_lin = blockIdx.x & 31;                 // head -> XCD pinning
    int rest = blockIdx.x >> 5;                     // 0..23
    int qt = rest % 12;
    int khalf = rest / 12;
    int b = head_lin >> 3, h = head_lin & 7;
    int tid = threadIdx.x;
    int wv = tid >> 6, lane = tid & 63;
    int col = lane & 15, quad = lane >> 4;
    size_t head = (size_t)b * HEADS_ + h;
    const u16* Qh = Qn + head * (size_t)N_ * DH_;
    const u16* Kh = Kn + head * (size_t)N_ * DH_ + (size_t)khalf * 1152 * DH_;
    const u16* Vh = Vt + head * (size_t)DH_ * N_;
    int q0 = qt * 192 + wv * 48;
    bf16x8 qfA0 = *(const bf16x8*)(Qh + (size_t)(q0 + col) * DH_ + quad*8);
    bf16x8 qfA1 = *(const bf16x8*)(Qh + (size_t)(q0 + col) * DH_ + 32 + quad*8);
    bf16x8 qfB0 = *(const bf16x8*)(Qh + (size_t)(q0 + 16 + col) * DH_ + quad*8);
    bf16x8 qfB1 = *(const bf16x8*)(Qh + (size_t)(q0 + 16 + col) * DH_ + 32 + quad*8);
    bf16x8 qfC0 = *(const bf16x8*)(Qh + (size_t)(q0 + 32 + col) * DH_ + quad*8);
    bf16x8 qfC1 = *(const bf16x8*)(Qh + (size_t)(q0 + 32 + col) * DH_ + 32 + quad*8);
    f32x4 z = {0.f, 0.f, 0.f, 0.f};
    f32x4 OA[4], OB[4], OC[4];
#pragma unroll
    for (int i = 0; i < 4; ++i) { OA[i] = z; OB[i] = z; OC[i] = z; }
    float lA = 0.f, lB = 0.f, lC = 0.f;
    int srow = tid >> 3, sseg = tid & 7;
    const u16* ksrc0 = Kh + (size_t)tid * 8;
    const u16* vsrc0 = Vh + (size_t)srow * N_ + khalf * 1152 + sseg * 8;

    uint4 k0 = *(const uint4*)(ksrc0);
    uint4 k1 = *(const uint4*)(ksrc0 + 2048);
    uint4 v0 = *(const uint4*)(vsrc0);
    uint4 v1 = *(const uint4*)(vsrc0 + (size_t)32 * N_);

    for (int kt = 0; kt < 18; ++kt) {
        *(uint4*)(&Kt[srow][sseg*8])      = k0;
        *(uint4*)(&Kt[32 + srow][sseg*8]) = k1;
        *(uint4*)(&Vtl[srow][sseg*8])      = v0;
        *(uint4*)(&Vtl[32 + srow][sseg*8]) = v1;
        __syncthreads();
        int ktn = kt + 1 < 18 ? kt + 1 : kt;
        k0 = *(const uint4*)(ksrc0 + (size_t)ktn * 4096);
        k1 = *(const uint4*)(ksrc0 + (size_t)ktn * 4096 + 2048);
        v0 = *(const uint4*)(vsrc0 + ktn * 64);
        v1 = *(const uint4*)(vsrc0 + (size_t)32 * N_ + ktn * 64);
        float rsA = 0.f, rsB = 0.f, rsC = 0.f;
#pragma unroll
        for (int nb = 0; nb < 4; ++nb) {
            bf16x8 kf0 = *(const bf16x8*)(&Kt[nb*16 + col][quad*8]);
            bf16x8 kf1 = *(const bf16x8*)(&Kt[nb*16 + col][32 + quad*8]);
            f32x4 a = MFMA16(kf0, qfA0, z);
            a = MFMA16(kf1, qfA1, a);
            f32x4 c = MFMA16(kf0, qfB0, z);
            c = MFMA16(kf1, qfB1, c);
            f32x4 e = MFMA16(kf0, qfC0, z);
            e = MFMA16(kf1, qfC1, e);
            float a0 = exp2f(fmaf(a[0], SCALE_LOG2E, -SCALE_LOG2E));
            float a1 = exp2f(fmaf(a[1], SCALE_LOG2E, -SCALE_LOG2E));
            float a2 = exp2f(fmaf(a[2], SCALE_LOG2E, -SCALE_LOG2E));
            float a3 = exp2f(fmaf(a[3], SCALE_LOG2E, -SCALE_LOG2E));
            float c0 = exp2f(fmaf(c[0], SCALE_LOG2E, -SCALE_LOG2E));
            float c1 = exp2f(fmaf(c[1], SCALE_LOG2E, -SCALE_LOG2E));
            float c2 = exp2f(fmaf(c[2], SCALE_LOG2E, -SCALE_LOG2E));
            float c3 = exp2f(fmaf(c[3], SCALE_LOG2E, -SCALE_LOG2E));
            float e0 = exp2f(fmaf(e[0], SCALE_LOG2E, -SCALE_LOG2E));
            float e1 = exp2f(fmaf(e[1], SCALE_LOG2E, -SCALE_LOG2E));
            float e2 = exp2f(fmaf(e[2], SCALE_LOG2E, -SCALE_LOG2E));
            float e3 = exp2f(fmaf(e[3], SCALE_LOG2E, -SCALE_LOG2E));
            rsA += (a0 + a1) + (a2 + a3);
            rsB += (c0 + c1) + (c2 + c3);
            rsC += (e0 + e1) + (e2 + e3);
            uint2 wA, wB, wC;
            wA.x = pk2(a0, a1); wA.y = pk2(a2, a3);
            wB.x = pk2(c0, c1); wB.y = pk2(c2, c3);
            wC.x = pk2(e0, e1); wC.y = pk2(e2, e3);
            *(uint2*)(&plds[wv][col][nb*16 + quad*4]) = wA;
            *(uint2*)(&plds[wv][16 + col][nb*16 + quad*4]) = wB;
            *(uint2*)(&plds[wv][32 + col][nb*16 + quad*4]) = wC;
        }
        lA += rsA; lB += rsB; lC += rsC;
        __asm__ volatile("" ::: "memory");
#pragma unroll
        for (int ks = 0; ks < 2; ++ks) {
            bf16x8 pfA = *(const bf16x8*)(&plds[wv][col][ks*32 + quad*8]);
            bf16x8 pfB = *(const bf16x8*)(&plds[wv][16 + col][ks*32 + quad*8]);
            bf16x8 pfC = *(const bf16x8*)(&plds[wv][32 + col][ks*32 + quad*8]);
#pragma unroll
            for (int nb = 0; nb < 4; ++nb) {
                bf16x8 vf = *(const bf16x8*)(&Vtl[nb*16 + col][ks*32 + quad*8]);
                OA[nb] = MFMA16(vf, pfA, OA[nb]);
                OB[nb] = MFMA16(vf, pfB, OB[nb]);
                OC[nb] = MFMA16(vf, pfC, OC[nb]);
            }
        }
        __asm__ volatile("" ::: "memory");
        __syncthreads();
    }
    lA += __shfl_xor(lA, 16); lA += __shfl_xor(lA, 32);
    lB += __shfl_xor(lB, 16); lB += __shfl_xor(lB, 32);
    lC += __shfl_xor(lC, 16); lC += __shfl_xor(lC, 32);
    float* dstA = Op + (((size_t)khalf * B_ + b) * N_ + q0 + col) * INNER_ + h * DH_;
    float* dstB = dstA + (size_t)16 * INNER_;
    float* dstC = dstA + (size_t)32 * INNER_;
#pragma unroll
    for (int nb = 0; nb < 4; ++nb) {
        *(f32x4*)(dstA + nb*16 + quad*4) = OA[nb];
        *(f32x4*)(dstB + nb*16 + quad*4) = OB[nb];
        *(f32x4*)(dstC + nb*16 + quad*4) = OC[nb];
    }
    if (quad == 0) {
        size_t lbase = (((size_t)khalf * B_ + b) * HEADS_ + h) * N_;
        lp[lbase + q0 + col] = lA;
        lp[lbase + q0 + 16 + col] = lB;
        lp[lbase + q0 + 32 + col] = lC;
    }
}

// ---------------- Kernel 2c: combine partials -> AO bf16 ----------------
__global__ __launch_bounds__(256) void k_comb(const float* __restrict__ Op,
                                              const float* __restrict__ lp,
                                              u16* __restrict__ AO) {
    int g = blockIdx.x * 256 + threadIdx.x;       // < 1,179,648 float4s per half
    int b = g / 294912;
    int rem = g % 294912;
    int n = rem >> 7;
    int i4 = rem & 127;
    int h = i4 >> 4;
    float4 a = ((const float4*)Op)[g];
    float4 c = ((const float4*)Op)[g + 1179648];
    float l = lp[((size_t)b * HEADS_ + h) * N_ + n] +
              lp[(((size_t)B_ + b) * HEADS_ + h) * N_ + n];
    float inv = 1.f / l;
    ushort4 o;
    o.x = f2bf((a.x + c.x) * inv);
    o.y = f2bf((a.y + c.y) * inv);
    o.z = f2bf((a.z + c.z) * inv);
    o.w = f2bf((a.w + c.w) * inv);
    ((ushort4*)AO)[g] = o;
}

// ---------------- Kernel 2b: fallback single-pass attention (R13 shape) ----------------
__global__ __launch_bounds__(256) void k_attn(const u16* __restrict__ Qn,
                                              const u16* __restrict__ Kn,
                                              const u16* __restrict__ Vt,
                                              u16* __restrict__ AO) {
    __shared__ __align__(16) u16 Kt[64][72];
    __shared__ __align__(16) u16 Vtl[64][72];
    __shared__ __align__(16) u16 plds[4][32][72];
    int head_lin = blockIdx.x & 31;
    int qt = blockIdx.x >> 5;
    int b = head_lin >> 3, h = head_lin & 7;
    int tid = threadIdx.x;
    int wv = tid >> 6, lane = tid & 63;
    int col = lane & 15, quad = lane >> 4;
    size_t head = (size_t)b * HEADS_ + h;
    const u16* Qh = Qn + head * (size_t)N_ * DH_;
    const u16* Kh = Kn + head * (size_t)N_ * DH_;
    const u16* Vh = Vt + head * (size_t)DH_ * N_;
    int q0 = qt * 128 + wv * 32;
    bf16x8 qfA0 = *(const bf16x8*)(Qh + (size_t)(q0 + col) * DH_ + quad*8);
    bf16x8 qfA1 = *(const bf16x8*)(Qh + (size_t)(q0 + col) * DH_ + 32 + quad*8);
    bf16x8 qfB0 = *(const bf16x8*)(Qh + (size_t)(q0 + 16 + col) * DH_ + quad*8);
    bf16x8 qfB1 = *(const bf16x8*)(Qh + (size_t)(q0 + 16 + col) * DH_ + 32 + quad*8);
    f32x4 z = {0.f, 0.f, 0.f, 0.f};
    f32x4 OA[4], OB[4];
#pragma unroll
    for (int i = 0; i < 4; ++i) { OA[i] = z; OB[i] = z; }
    float lA = 0.f, lB = 0.f;
    int srow = tid >> 3, sseg = tid & 7;
    const u16* ksrc0 = Kh + (size_t)tid * 8;
    const u16* vsrc0 = Vh + (size_t)srow * N_ + sseg * 8;
    uint4 k0 = *(const uint4*)(ksrc0);
    uint4 k1 = *(const uint4*)(ksrc0 + 2048);
    uint4 v0 = *(const uint4*)(vsrc0);
    uint4 v1 = *(const uint4*)(vsrc0 + (size_t)32 * N_);
    for (int kt = 0; kt < N_/64; ++kt) {
        *(uint4*)(&Kt[srow][sseg*8])      = k0;
        *(uint4*)(&Kt[32 + srow][sseg*8]) = k1;
        *(uint4*)(&Vtl[srow][sseg*8])      = v0;
        *(uint4*)(&Vtl[32 + srow][sseg*8]) = v1;
        __syncthreads();
        int ktn = kt + 1 < N_/64 ? kt + 1 : kt;
        k0 = *(const uint4*)(ksrc0 + (size_t)ktn * 4096);
        k1 = *(const uint4*)(ksrc0 + (size_t)ktn * 4096 + 2048);
        v0 = *(const uint4*)(vsrc0 + ktn * 64);
        v1 = *(const uint4*)(vsrc0 + (size_t)32 * N_ + ktn * 64);
        float rsA = 0.f, rsB = 0.f;
#pragma unroll
        for (int nb = 0; nb < 4; ++nb) {
            bf16x8 kf0 = *(const bf16x8*)(&Kt[nb*16 + col][quad*8]);
            bf16x8 kf1 = *(const bf16x8*)(&Kt[nb*16 + col][32 + quad*8]);
            f32x4 a = MFMA16(kf0, qfA0, z);
            a = MFMA16(kf1, qfA1, a);
            f32x4 c = MFMA16(kf0, qfB0, z);
            c = MFMA16(kf1, qfB1, c);
            float a0 = exp2f(fmaf(a[0], SCALE_LOG2E, -SCALE_LOG2E));
            float a1 = exp2f(fmaf(a[1], SCALE_LOG2E, -SCALE_LOG2E));
            float a2 = exp2f(fmaf(a[2], SCALE_LOG2E, -SCALE_LOG2E));
            float a3 = exp2f(fmaf(a[3], SCALE_LOG2E, -SCALE_LOG2E));
            float c0 = exp2f(fmaf(c[0], SCALE_LOG2E, -SCALE_LOG2E));
            float c1 = exp2f(fmaf(c[1], SCALE_LOG2E, -SCALE_LOG2E));
            float c2 = exp2f(fmaf(c[2], SCALE_LOG2E, -SCALE_LOG2E));
            float c3 = exp2f(fmaf(c[3], SCALE_LOG2E, -SCALE_LOG2E));
            rsA += (a0 + a1) + (a2 + a3);
            rsB += (c0 + c1) + (c2 + c3);
            uint2 wA, wB;
            wA.x = pk2(a0, a1); wA.y = pk2(a2, a3);
            wB.x = pk2(c0, c1); wB.y = pk2(c2, c3);
            *(uint2*)(&plds[wv][col][nb*16 + quad*4]) = wA;
            *(uint2*)(&plds[wv][16 + col][nb*16 + quad*4]) = wB;
        }
        lA += rsA; lB += rsB;
        __asm__ volatile("" ::: "memory");
#pragma unroll
        for (int ks = 0; ks < 2; ++ks) {
            bf16x8 pfA = *(const bf16x8*)(&plds[wv][col][ks*32 + quad*8]);
            bf16x8 pfB = *(const bf16x8*)(&plds[wv][16 + col][ks*32 + quad*8]);
#pragma unroll
            for (int nb = 0; nb < 4; ++nb) {
                bf16x8 vf = *(const bf16x8*)(&Vtl[nb*16 + col][ks*32 + quad*8]);
                OA[nb] = MFMA16(vf, pfA, OA[nb]);
                OB[nb] = MFMA16(vf, pfB, OB[nb]);
            }
        }
        __asm__ volatile("" ::: "memory");
        __syncthreads();
    }
    lA += __shfl_xor(lA, 16); lA += __shfl_xor(lA, 32);
    lB += __shfl_xor(lB, 16); lB += __shfl_xor(lB, 32);
    float linvA = 1.f / lA, linvB = 1.f / lB;
    u16* dstA = AO + ((size_t)b * N_ + q0 + col) * INNER_ + h * DH_;
    u16* dstB = AO + ((size_t)b * N_ + q0 + 16 + col) * INNER_ + h * DH_;
#pragma unroll
    for (int nb = 0; nb < 4; ++nb) {
        uint2 wA, wB;
        wA.x = pk2(OA[nb][0] * linvA, OA[nb][1] * linvA);
        wA.y = pk2(OA[nb][2] * linvA, OA[nb][3] * linvA);
        wB.x = pk2(OB[nb][0] * linvB, OB[nb][1] * linvB);
        wB.y = pk2(OB[nb][2] * linvB, OB[nb][3] * linvB);
        *(uint2*)(dstA + nb*16 + quad*4) = wA;
        *(uint2*)(dstB + nb*16 + quad*4) = wB;
    }
}

// ---------------- Kernel 3: output projection (LDS-staged) + bias ----------------
__global__ __launch_bounds__(256) void k_proj(const u16* __restrict__ w_out,
                                              const float* __restrict__ b_out,
                                              const u16* __restrict__ AO,
                                              float* __restrict__ out) {
    __shared__ __align__(16) u16 Wt[64][264];
    __shared__ __align__(16) u16 At[64][264];
    int mt = blockIdx.x, nt = blockIdx.y, b = blockIdx.z;
    int tid = threadIdx.x;
    int wv = tid >> 6, lane = tid & 63;
    int col = lane & 15, quad = lane >> 4;
    int o0b = mt * 64;
    const u16* wtile = w_out + (size_t)o0b * INNER_;
    const u16* atile = AO + ((size_t)b * N_ + nt*64) * INNER_;
    f32x4 z = {0.f, 0.f, 0.f, 0.f};
    f32x4 acc[4]; acc[0]=z; acc[1]=z; acc[2]=z; acc[3]=z;
#pragma unroll
    for (int half = 0; half < 2; ++half) {
        if (half) __syncthreads();
#pragma unroll
        for (int p = 0; p < 8; ++p) {
            int c = p * 256 + tid;
            int row = c >> 5, seg = c & 31;
            *(uint4*)(&Wt[row][seg*8]) =
                *(const uint4*)(wtile + (size_t)row * INNER_ + half*256 + seg*8);
            *(uint4*)(&At[row][seg*8]) =
                *(const uint4*)(atile + (size_t)row * INNER_ + half*256 + seg*8);
        }
        __syncthreads();
#pragma unroll
        for (int ks = 0; ks < 8; ++ks) {
            bf16x8 af = *(const bf16x8*)(&Wt[wv*16 + col][ks*32 + quad*8]);
#pragma unroll
            for (int nb = 0; nb < 4; ++nb) {
                bf16x8 bfv = *(const bf16x8*)(&At[nb*16 + col][ks*32 + quad*8]);
                acc[nb] = MFMA16(af, bfv, acc[nb]);
            }
        }
    }
    int o0 = o0b + wv * 16;
    float bias[4];
#pragma unroll
    for (int r = 0; r < 4; ++r) bias[r] = b_out[o0 + quad*4 + r];
    float* dst = out + ((size_t)b * C_ + o0) * N_ + nt*64;
#pragma unroll
    for (int nb = 0; nb < 4; ++nb)
#pragma unroll
        for (int r = 0; r < 4; ++r)
            dst[(size_t)(quad*4 + r) * N_ + nb*16 + col] = acc[nb][r] + bias[r];
}

// ---------------- launch ----------------
extern "C" void kernel_launch(void* const* d_in, const int* in_sizes, int n_in,
                              void* d_out, int out_size, void* d_ws, size_t ws_size,
                              hipStream_t stream) {
    const float* x     = (const float*)d_in[0];
    const float* w_qkv = (const float*)d_in[1];
    const float* w_out = (const float*)d_in[2];
    const float* b_out = (const float*)d_in[3];
    float* out = (float*)d_out;

    char* ws = (char*)d_ws;
    u16* xT  = (u16*)(ws);
    u16* Qn  = (u16*)(ws + 4718592);
    u16* Kn  = (u16*)(ws + 14155776);
    u16* Vt  = (u16*)(ws + 23592960);
    u16* AO  = (u16*)(ws + 33030144);
    u16* wqb = (u16*)(ws + 42467328);
    u16* wob = (u16*)(ws + 43253760);
    float* Op = (float*)(ws + 43515904);   // 2 x 18,874,368 B f32 partials
    float* lp = (float*)(ws + 81264640);   // 2 x 294,912 B f32 row sums
    const size_t need = 81854464;

    hipLaunchKernelGGL(k_prep, dim3(1088), dim3(256), 0, stream, x, xT, w_qkv, wqb, w_out, wob);
    hipLaunchKernelGGL(k_qkv,  dim3(24, N_/64, B_), dim3(256), 0, stream, wqb, xT, Qn, Kn, Vt);
    if (ws_size >= need) {
        hipLaunchKernelGGL(k_attn_split, dim3(768), dim3(256), 0, stream, Qn, Kn, Vt, Op, lp);
        hipLaunchKernelGGL(k_comb, dim3(4608), dim3(256), 0, stream, Op, lp, AO);
    } else {
        hipLaunchKernelGGL(k_attn, dim3((N_/128) * 32), dim3(256), 0, stream, Qn, Kn, Vt, AO);
    }
    hipLaunchKernelGGL(k_proj, dim3(C_/64, N_/64, B_), dim3(256), 0, stream, wob, b_out, AO, out);
}

// Round 16
// 190.688 us; speedup vs baseline: 1.1469x; 1.0289x over previous
//
#include <hip/hip_runtime.h>

typedef unsigned short u16;
typedef __attribute__((ext_vector_type(8))) short bf16x8;
typedef __attribute__((ext_vector_type(4))) float f32x4;

#define MFMA16(A,B,C) __builtin_amdgcn_mfma_f32_16x16x32_bf16(A,B,C,0,0,0)

#define B_ 4
#define C_ 256
#define N_ 2304
#define HEADS_ 8
#define DH_ 64
#define INNER_ 512
#define SCALE_LOG2E 14.426950408889634f   // 10 * log2(e); also the fixed max bias

__device__ __forceinline__ u16 f2bf(float f) {
    union { float f; unsigned int u; } v; v.f = f;
    unsigned int r = v.u + 0x7fffu + ((v.u >> 16) & 1u);
    return (u16)(r >> 16);
}
__device__ __forceinline__ float bf2f(u16 h) {
    union { unsigned int u; float f; } v; v.u = ((unsigned int)h) << 16;
    return v.f;
}
// pack two floats to bf16x2 (round-half-up) in 3 VALU ops
__device__ __forceinline__ unsigned int pk2(float a, float b) {
    union { float f; unsigned int u; } va, vb; va.f = a; vb.f = b;
    return __builtin_amdgcn_perm(vb.u + 0x8000u, va.u + 0x8000u, 0x07060302u);
}

// ---------------- Kernel P: fused prep (transpose x + convert weights) ----------------
__global__ __launch_bounds__(256) void k_prep(const float* __restrict__ x,
                                              u16* __restrict__ xT,
                                              const float* __restrict__ w_qkv,
                                              u16* __restrict__ wqb,
                                              const float* __restrict__ w_out,
                                              u16* __restrict__ wob) {
    __shared__ float tile[64][65];
    int idx = blockIdx.x;
    int t = threadIdx.x;
    if (idx < 576) {
        int b = idx / 144, rem = idx % 144;
        int n0 = (rem >> 2) * 64, c0 = (rem & 3) * 64;
        const float* xb = x + (size_t)b * C_ * N_;
        u16* xTb = xT + (size_t)b * N_ * C_;
        int r = t >> 4;
        int q4 = (t & 15) * 4;
#pragma unroll
        for (int pass = 0; pass < 4; ++pass) {
            int c = r + pass * 16;
            float4 v = *(const float4*)(xb + (size_t)(c0 + c) * N_ + n0 + q4);
            tile[c][q4+0] = v.x; tile[c][q4+1] = v.y; tile[c][q4+2] = v.z; tile[c][q4+3] = v.w;
        }
        __syncthreads();
#pragma unroll
        for (int pass = 0; pass < 4; ++pass) {
            int n = r + pass * 16;
            ushort4 o;
            o.x = f2bf(tile[q4+0][n]); o.y = f2bf(tile[q4+1][n]);
            o.z = f2bf(tile[q4+2][n]); o.w = f2bf(tile[q4+3][n]);
            *(ushort4*)(xTb + (size_t)(n0 + n) * C_ + c0 + q4) = o;
        }
    } else if (idx < 960) {
        int i = (idx - 576) * 256 + t;
        float4 v = ((const float4*)w_qkv)[i];
        ushort4 o;
        o.x = f2bf(v.x); o.y = f2bf(v.y); o.z = f2bf(v.z); o.w = f2bf(v.w);
        ((ushort4*)wqb)[i] = o;
    } else {
        int i = (idx - 960) * 256 + t;
        float4 v = ((const float4*)w_out)[i];
        ushort4 o;
        o.x = f2bf(v.x); o.y = f2bf(v.y); o.z = f2bf(v.z); o.w = f2bf(v.w);
        ((ushort4*)wob)[i] = o;
    }
}

// ---------------- Kernel 1: QKV GEMM (LDS-staged) + l2norm(q,k) ----------------
__global__ __launch_bounds__(256) void k_qkv(const u16* __restrict__ w_qkv,
                                             const u16* __restrict__ xT,
                                             u16* __restrict__ Qn,
                                             u16* __restrict__ Kn,
                                             u16* __restrict__ Vt) {
    __shared__ __align__(16) u16 Wt[64][264];
    __shared__ __align__(16) u16 Xt[64][264];
    int mt = blockIdx.x, nt = blockIdx.y, b = blockIdx.z;
    int tid = threadIdx.x;
    int wv = tid >> 6, lane = tid & 63;
    int col = lane & 15, quad = lane >> 4;
    int o0 = mt * 64;
    const u16* wtile = w_qkv + (size_t)o0 * C_;
    const u16* xtile = xT + ((size_t)b * N_ + nt*64) * C_;
#pragma unroll
    for (int p = 0; p < 8; ++p) {
        int c = p * 256 + tid;
        int row = c >> 5, seg = c & 31;
        *(uint4*)(&Wt[row][seg*8]) = *(const uint4*)(wtile + (size_t)row * C_ + seg*8);
        *(uint4*)(&Xt[row][seg*8]) = *(const uint4*)(xtile + (size_t)row * C_ + seg*8);
    }
    __syncthreads();
    f32x4 z = {0.f, 0.f, 0.f, 0.f};
    f32x4 acc[4]; acc[0]=z; acc[1]=z; acc[2]=z; acc[3]=z;
#pragma unroll
    for (int ks = 0; ks < 8; ++ks) {
        bf16x8 bfrag = *(const bf16x8*)(&Xt[wv*16 + col][ks*32 + quad*8]);
#pragma unroll
        for (int mb = 0; mb < 4; ++mb) {
            bf16x8 afrag = *(const bf16x8*)(&Wt[mb*16 + col][ks*32 + quad*8]);
            acc[mb] = MFMA16(afrag, bfrag, acc[mb]);
        }
    }
    int n = nt * 64 + wv * 16 + col;
    int which = mt >> 3, h = mt & 7;
    if (which < 2) {
        float s = 0.f;
#pragma unroll
        for (int mb = 0; mb < 4; ++mb)
#pragma unroll
            for (int r = 0; r < 4; ++r) s += acc[mb][r] * acc[mb][r];
        s += __shfl_xor(s, 16);
        s += __shfl_xor(s, 32);
        float inv = 1.f / fmaxf(sqrtf(s), 1e-12f);
        u16* dst = (which == 0 ? Qn : Kn) + (((size_t)b * HEADS_ + h) * N_ + n) * DH_;
#pragma unroll
        for (int mb = 0; mb < 4; ++mb) {
            ushort4 o;
            o.x = f2bf(acc[mb][0] * inv); o.y = f2bf(acc[mb][1] * inv);
            o.z = f2bf(acc[mb][2] * inv); o.w = f2bf(acc[mb][3] * inv);
            *(ushort4*)(dst + mb*16 + quad*4) = o;
        }
    } else {
        u16* dst = Vt + ((size_t)b * HEADS_ + h) * (size_t)DH_ * N_;
#pragma unroll
        for (int mb = 0; mb < 4; ++mb)
#pragma unroll
            for (int r = 0; r < 4; ++r)
                dst[(size_t)(mb*16 + quad*4 + r) * N_ + n] = f2bf(acc[mb][r]);
    }
}

// ---------------- Kernel 2a: flash attention, 4-way K-split, bf16 partials ----------
// blockIdx.x = (ksplit*18 + qt)*32 + head_lin. Grid 2304 = exactly 9 blocks/CU.
// Each block: 128-q tile, 576 keys (9 iters). 2 q-subtiles/wave (R14 shape, 68 VGPR).
// Fixed-max softmax => partials combine linearly in k_comb.
__global__ __launch_bounds__(256) void k_attn_split(const u16* __restrict__ Qn,
                                                    const u16* __restrict__ Kn,
                                                    const u16* __restrict__ Vt,
                                                    u16* __restrict__ Opb,
                                                    float* __restrict__ lp) {
    __shared__ __align__(16) u16 Kt[64][72];
    __shared__ __align__(16) u16 Vtl[64][72];
    __shared__ __align__(16) u16 plds[4][32][72];
    int head_lin = blockIdx.x & 31;                 // head -> XCD pinning
    int rest = blockIdx.x >> 5;                     // 0..71
    int qt = rest % 18;
    int ksplit = rest / 18;                         // 0..3
    int b = head_lin >> 3, h = head_lin & 7;
    int tid = threadIdx.x;
    int wv = tid >> 6, lane = tid & 63;
    int col = lane & 15, quad = lane >> 4;
    size_t head = (size_t)b * HEADS_ + h;
    const u16* Qh = Qn + head * (size_t)N_ * DH_;
    const u16* Kh = Kn + head * (size_t)N_ * DH_ + (size_t)ksplit * 576 * DH_;
    const u16* Vh = Vt + head * (size_t)DH_ * N_;
    int q0 = qt * 128 + wv * 32;
    bf16x8 qfA0 = *(const bf16x8*)(Qh + (size_t)(q0 + col) * DH_ + quad*8);
    bf16x8 qfA1 = *(const bf16x8*)(Qh + (size_t)(q0 + col) * DH_ + 32 + quad*8);
    bf16x8 qfB0 = *(const bf16x8*)(Qh + (size_t)(q0 + 16 + col) * DH_ + quad*8);
    bf16x8 qfB1 = *(const bf16x8*)(Qh + (size_t)(q0 + 16 + col) * DH_ + 32 + quad*8);
    f32x4 z = {0.f, 0.f, 0.f, 0.f};
    f32x4 OA[4], OB[4];
#pragma unroll
    for (int i = 0; i < 4; ++i) { OA[i] = z; OB[i] = z; }
    float lA = 0.f, lB = 0.f;
    int srow = tid >> 3, sseg = tid & 7;
    const u16* ksrc0 = Kh + (size_t)tid * 8;
    const u16* vsrc0 = Vh + (size_t)srow * N_ + ksplit * 576 + sseg * 8;

    uint4 k0 = *(const uint4*)(ksrc0);
    uint4 k1 = *(const uint4*)(ksrc0 + 2048);
    uint4 v0 = *(const uint4*)(vsrc0);
    uint4 v1 = *(const uint4*)(vsrc0 + (size_t)32 * N_);

    for (int kt = 0; kt < 9; ++kt) {
        *(uint4*)(&Kt[srow][sseg*8])      = k0;
        *(uint4*)(&Kt[32 + srow][sseg*8]) = k1;
        *(uint4*)(&Vtl[srow][sseg*8])      = v0;
        *(uint4*)(&Vtl[32 + srow][sseg*8]) = v1;
        __syncthreads();
        int ktn = kt + 1 < 9 ? kt + 1 : kt;
        k0 = *(const uint4*)(ksrc0 + (size_t)ktn * 4096);
        k1 = *(const uint4*)(ksrc0 + (size_t)ktn * 4096 + 2048);
        v0 = *(const uint4*)(vsrc0 + ktn * 64);
        v1 = *(const uint4*)(vsrc0 + (size_t)32 * N_ + ktn * 64);
        float rsA = 0.f, rsB = 0.f;
#pragma unroll
        for (int nb = 0; nb < 4; ++nb) {
            bf16x8 kf0 = *(const bf16x8*)(&Kt[nb*16 + col][quad*8]);
            bf16x8 kf1 = *(const bf16x8*)(&Kt[nb*16 + col][32 + quad*8]);
            f32x4 a = MFMA16(kf0, qfA0, z);
            a = MFMA16(kf1, qfA1, a);
            f32x4 c = MFMA16(kf0, qfB0, z);
            c = MFMA16(kf1, qfB1, c);
            float a0 = exp2f(fmaf(a[0], SCALE_LOG2E, -SCALE_LOG2E));
            float a1 = exp2f(fmaf(a[1], SCALE_LOG2E, -SCALE_LOG2E));
            float a2 = exp2f(fmaf(a[2], SCALE_LOG2E, -SCALE_LOG2E));
            float a3 = exp2f(fmaf(a[3], SCALE_LOG2E, -SCALE_LOG2E));
            float c0 = exp2f(fmaf(c[0], SCALE_LOG2E, -SCALE_LOG2E));
            float c1 = exp2f(fmaf(c[1], SCALE_LOG2E, -SCALE_LOG2E));
            float c2 = exp2f(fmaf(c[2], SCALE_LOG2E, -SCALE_LOG2E));
            float c3 = exp2f(fmaf(c[3], SCALE_LOG2E, -SCALE_LOG2E));
            rsA += (a0 + a1) + (a2 + a3);
            rsB += (c0 + c1) + (c2 + c3);
            uint2 wA, wB;
            wA.x = pk2(a0, a1); wA.y = pk2(a2, a3);
            wB.x = pk2(c0, c1); wB.y = pk2(c2, c3);
            *(uint2*)(&plds[wv][col][nb*16 + quad*4]) = wA;
            *(uint2*)(&plds[wv][16 + col][nb*16 + quad*4]) = wB;
        }
        lA += rsA; lB += rsB;
        __asm__ volatile("" ::: "memory");
#pragma unroll
        for (int ks = 0; ks < 2; ++ks) {
            bf16x8 pfA = *(const bf16x8*)(&plds[wv][col][ks*32 + quad*8]);
            bf16x8 pfB = *(const bf16x8*)(&plds[wv][16 + col][ks*32 + quad*8]);
#pragma unroll
            for (int nb = 0; nb < 4; ++nb) {
                bf16x8 vf = *(const bf16x8*)(&Vtl[nb*16 + col][ks*32 + quad*8]);
                OA[nb] = MFMA16(vf, pfA, OA[nb]);
                OB[nb] = MFMA16(vf, pfB, OB[nb]);
            }
        }
        __asm__ volatile("" ::: "memory");
        __syncthreads();
    }
    lA += __shfl_xor(lA, 16); lA += __shfl_xor(lA, 32);
    lB += __shfl_xor(lB, 16); lB += __shfl_xor(lB, 32);
    // unnormalized bf16 partials (footprint = old 2-way f32)
    u16* dstA = Opb + (((size_t)ksplit * B_ + b) * N_ + q0 + col) * INNER_ + h * DH_;
    u16* dstB = dstA + (size_t)16 * INNER_;
#pragma unroll
    for (int nb = 0; nb < 4; ++nb) {
        uint2 wA, wB;
        wA.x = pk2(OA[nb][0], OA[nb][1]); wA.y = pk2(OA[nb][2], OA[nb][3]);
        wB.x = pk2(OB[nb][0], OB[nb][1]); wB.y = pk2(OB[nb][2], OB[nb][3]);
        *(uint2*)(dstA + nb*16 + quad*4) = wA;
        *(uint2*)(dstB + nb*16 + quad*4) = wB;
    }
    if (quad == 0) {
        size_t lbase = (((size_t)ksplit * B_ + b) * HEADS_ + h) * N_;
        lp[lbase + q0 + col] = lA;
        lp[lbase + q0 + 16 + col] = lB;
    }
}

// ---------------- Kernel 2c: combine 4 bf16 partials -> AO bf16 ----------------
__global__ __launch_bounds__(256) void k_comb(const u16* __restrict__ Opb,
                                              const float* __restrict__ lp,
                                              u16* __restrict__ AO) {
    int g = blockIdx.x * 256 + threadIdx.x;       // over 1,179,648 ushort4s
    int b = g / 294912;
    int rem = g % 294912;
    int n = rem >> 7;
    int i4 = rem & 127;
    int h = i4 >> 4;
    float s0 = 0.f, s1 = 0.f, s2 = 0.f, s3 = 0.f, l = 0.f;
#pragma unroll
    for (int s = 0; s < 4; ++s) {
        ushort4 p = ((const ushort4*)Opb)[g + (size_t)s * 1179648];
        s0 += bf2f(p.x); s1 += bf2f(p.y); s2 += bf2f(p.z); s3 += bf2f(p.w);
        l += lp[(((size_t)s * B_ + b) * HEADS_ + h) * N_ + n];
    }
    float inv = 1.f / l;
    ushort4 o;
    o.x = f2bf(s0 * inv); o.y = f2bf(s1 * inv);
    o.z = f2bf(s2 * inv); o.w = f2bf(s3 * inv);
    ((ushort4*)AO)[g] = o;
}

// ---------------- Kernel 2b: fallback single-pass attention (R13 shape) ----------------
__global__ __launch_bounds__(256) void k_attn(const u16* __restrict__ Qn,
                                              const u16* __restrict__ Kn,
                                              const u16* __restrict__ Vt,
                                              u16* __restrict__ AO) {
    __shared__ __align__(16) u16 Kt[64][72];
    __shared__ __align__(16) u16 Vtl[64][72];
    __shared__ __align__(16) u16 plds[4][32][72];
    int head_lin = blockIdx.x & 31;
    int qt = blockIdx.x >> 5;
    int b = head_lin >> 3, h = head_lin & 7;
    int tid = threadIdx.x;
    int wv = tid >> 6, lane = tid & 63;
    int col = lane & 15, quad = lane >> 4;
    size_t head = (size_t)b * HEADS_ + h;
    const u16* Qh = Qn + head * (size_t)N_ * DH_;
    const u16* Kh = Kn + head * (size_t)N_ * DH_;
    const u16* Vh = Vt + head * (size_t)DH_ * N_;
    int q0 = qt * 128 + wv * 32;
    bf16x8 qfA0 = *(const bf16x8*)(Qh + (size_t)(q0 + col) * DH_ + quad*8);
    bf16x8 qfA1 = *(const bf16x8*)(Qh + (size_t)(q0 + col) * DH_ + 32 + quad*8);
    bf16x8 qfB0 = *(const bf16x8*)(Qh + (size_t)(q0 + 16 + col) * DH_ + quad*8);
    bf16x8 qfB1 = *(const bf16x8*)(Qh + (size_t)(q0 + 16 + col) * DH_ + 32 + quad*8);
    f32x4 z = {0.f, 0.f, 0.f, 0.f};
    f32x4 OA[4], OB[4];
#pragma unroll
    for (int i = 0; i < 4; ++i) { OA[i] = z; OB[i] = z; }
    float lA = 0.f, lB = 0.f;
    int srow = tid >> 3, sseg = tid & 7;
    const u16* ksrc0 = Kh + (size_t)tid * 8;
    const u16* vsrc0 = Vh + (size_t)srow * N_ + sseg * 8;
    uint4 k0 = *(const uint4*)(ksrc0);
    uint4 k1 = *(const uint4*)(ksrc0 + 2048);
    uint4 v0 = *(const uint4*)(vsrc0);
    uint4 v1 = *(const uint4*)(vsrc0 + (size_t)32 * N_);
    for (int kt = 0; kt < N_/64; ++kt) {
        *(uint4*)(&Kt[srow][sseg*8])      = k0;
        *(uint4*)(&Kt[32 + srow][sseg*8]) = k1;
        *(uint4*)(&Vtl[srow][sseg*8])      = v0;
        *(uint4*)(&Vtl[32 + srow][sseg*8]) = v1;
        __syncthreads();
        int ktn = kt + 1 < N_/64 ? kt + 1 : kt;
        k0 = *(const uint4*)(ksrc0 + (size_t)ktn * 4096);
        k1 = *(const uint4*)(ksrc0 + (size_t)ktn * 4096 + 2048);
        v0 = *(const uint4*)(vsrc0 + ktn * 64);
        v1 = *(const uint4*)(vsrc0 + (size_t)32 * N_ + ktn * 64);
        float rsA = 0.f, rsB = 0.f;
#pragma unroll
        for (int nb = 0; nb < 4; ++nb) {
            bf16x8 kf0 = *(const bf16x8*)(&Kt[nb*16 + col][quad*8]);
            bf16x8 kf1 = *(const bf16x8*)(&Kt[nb*16 + col][32 + quad*8]);
            f32x4 a = MFMA16(kf0, qfA0, z);
            a = MFMA16(kf1, qfA1, a);
            f32x4 c = MFMA16(kf0, qfB0, z);
            c = MFMA16(kf1, qfB1, c);
            float a0 = exp2f(fmaf(a[0], SCALE_LOG2E, -SCALE_LOG2E));
            float a1 = exp2f(fmaf(a[1], SCALE_LOG2E, -SCALE_LOG2E));
            float a2 = exp2f(fmaf(a[2], SCALE_LOG2E, -SCALE_LOG2E));
            float a3 = exp2f(fmaf(a[3], SCALE_LOG2E, -SCALE_LOG2E));
            float c0 = exp2f(fmaf(c[0], SCALE_LOG2E, -SCALE_LOG2E));
            float c1 = exp2f(fmaf(c[1], SCALE_LOG2E, -SCALE_LOG2E));
            float c2 = exp2f(fmaf(c[2], SCALE_LOG2E, -SCALE_LOG2E));
            float c3 = exp2f(fmaf(c[3], SCALE_LOG2E, -SCALE_LOG2E));
            rsA += (a0 + a1) + (a2 + a3);
            rsB += (c0 + c1) + (c2 + c3);
            uint2 wA, wB;
            wA.x = pk2(a0, a1); wA.y = pk2(a2, a3);
            wB.x = pk2(c0, c1); wB.y = pk2(c2, c3);
            *(uint2*)(&plds[wv][col][nb*16 + quad*4]) = wA;
            *(uint2*)(&plds[wv][16 + col][nb*16 + quad*4]) = wB;
        }
        lA += rsA; lB += rsB;
        __asm__ volatile("" ::: "memory");
#pragma unroll
        for (int ks = 0; ks < 2; ++ks) {
            bf16x8 pfA = *(const bf16x8*)(&plds[wv][col][ks*32 + quad*8]);
            bf16x8 pfB = *(const bf16x8*)(&plds[wv][16 + col][ks*32 + quad*8]);
#pragma unroll
            for (int nb = 0; nb < 4; ++nb) {
                bf16x8 vf = *(const bf16x8*)(&Vtl[nb*16 + col][ks*32 + quad*8]);
                OA[nb] = MFMA16(vf, pfA, OA[nb]);
                OB[nb] = MFMA16(vf, pfB, OB[nb]);
            }
        }
        __asm__ volatile("" ::: "memory");
        __syncthreads();
    }
    lA += __shfl_xor(lA, 16); lA += __shfl_xor(lA, 32);
    lB += __shfl_xor(lB, 16); lB += __shfl_xor(lB, 32);
    float linvA = 1.f / lA, linvB = 1.f / lB;
    u16* dstA = AO + ((size_t)b * N_ + q0 + col) * INNER_ + h * DH_;
    u16* dstB = AO + ((size_t)b * N_ + q0 + 16 + col) * INNER_ + h * DH_;
#pragma unroll
    for (int nb = 0; nb < 4; ++nb) {
        uint2 wA, wB;
        wA.x = pk2(OA[nb][0] * linvA, OA[nb][1] * linvA);
        wA.y = pk2(OA[nb][2] * linvA, OA[nb][3] * linvA);
        wB.x = pk2(OB[nb][0] * linvB, OB[nb][1] * linvB);
        wB.y = pk2(OB[nb][2] * linvB, OB[nb][3] * linvB);
        *(uint2*)(dstA + nb*16 + quad*4) = wA;
        *(uint2*)(dstB + nb*16 + quad*4) = wB;
    }
}

// ---------------- Kernel 3: output projection (LDS-staged) + bias ----------------
__global__ __launch_bounds__(256) void k_proj(const u16* __restrict__ w_out,
                                              const float* __restrict__ b_out,
                                              const u16* __restrict__ AO,
                                              float* __restrict__ out) {
    __shared__ __align__(16) u16 Wt[64][264];
    __shared__ __align__(16) u16 At[64][264];
    int mt = blockIdx.x, nt = blockIdx.y, b = blockIdx.z;
    int tid = threadIdx.x;
    int wv = tid >> 6, lane = tid & 63;
    int col = lane & 15, quad = lane >> 4;
    int o0b = mt * 64;
    const u16* wtile = w_out + (size_t)o0b * INNER_;
    const u16* atile = AO + ((size_t)b * N_ + nt*64) * INNER_;
    f32x4 z = {0.f, 0.f, 0.f, 0.f};
    f32x4 acc[4]; acc[0]=z; acc[1]=z; acc[2]=z; acc[3]=z;
#pragma unroll
    for (int half = 0; half < 2; ++half) {
        if (half) __syncthreads();
#pragma unroll
        for (int p = 0; p < 8; ++p) {
            int c = p * 256 + tid;
            int row = c >> 5, seg = c & 31;
            *(uint4*)(&Wt[row][seg*8]) =
                *(const uint4*)(wtile + (size_t)row * INNER_ + half*256 + seg*8);
            *(uint4*)(&At[row][seg*8]) =
                *(const uint4*)(atile + (size_t)row * INNER_ + half*256 + seg*8);
        }
        __syncthreads();
#pragma unroll
        for (int ks = 0; ks < 8; ++ks) {
            bf16x8 af = *(const bf16x8*)(&Wt[wv*16 + col][ks*32 + quad*8]);
#pragma unroll
            for (int nb = 0; nb < 4; ++nb) {
                bf16x8 bfv = *(const bf16x8*)(&At[nb*16 + col][ks*32 + quad*8]);
                acc[nb] = MFMA16(af, bfv, acc[nb]);
            }
        }
    }
    int o0 = o0b + wv * 16;
    float bias[4];
#pragma unroll
    for (int r = 0; r < 4; ++r) bias[r] = b_out[o0 + quad*4 + r];
    float* dst = out + ((size_t)b * C_ + o0) * N_ + nt*64;
#pragma unroll
    for (int nb = 0; nb < 4; ++nb)
#pragma unroll
        for (int r = 0; r < 4; ++r)
            dst[(size_t)(quad*4 + r) * N_ + nb*16 + col] = acc[nb][r] + bias[r];
}

// ---------------- launch ----------------
extern "C" void kernel_launch(void* const* d_in, const int* in_sizes, int n_in,
                              void* d_out, int out_size, void* d_ws, size_t ws_size,
                              hipStream_t stream) {
    const float* x     = (const float*)d_in[0];
    const float* w_qkv = (const float*)d_in[1];
    const float* w_out = (const float*)d_in[2];
    const float* b_out = (const float*)d_in[3];
    float* out = (float*)d_out;

    char* ws = (char*)d_ws;
    u16* xT  = (u16*)(ws);                 // dead after k_qkv; lp reuses this region
    u16* Qn  = (u16*)(ws + 4718592);
    u16* Kn  = (u16*)(ws + 14155776);
    u16* Vt  = (u16*)(ws + 23592960);
    u16* AO  = (u16*)(ws + 33030144);
    u16* wqb = (u16*)(ws + 42467328);
    u16* wob = (u16*)(ws + 43253760);
    u16* Opb = (u16*)(ws + 43515904);      // 4 x 9,437,184 B bf16 partials = 37,748,736 B
    float* lp = (float*)(ws + 1179648);    // 4 x 294,912 B f32 row sums, inside dead xT region
    const size_t need = 81854464;          // proven-available watermark (R14)

    hipLaunchKernelGGL(k_prep, dim3(1088), dim3(256), 0, stream, x, xT, w_qkv, wqb, w_out, wob);
    hipLaunchKernelGGL(k_qkv,  dim3(24, N_/64, B_), dim3(256), 0, stream, wqb, xT, Qn, Kn, Vt);
    if (ws_size >= need) {
        hipLaunchKernelGGL(k_attn_split, dim3(2304), dim3(256), 0, stream, Qn, Kn, Vt, Opb, lp);
        hipLaunchKernelGGL(k_comb, dim3(4608), dim3(256), 0, stream, Opb, lp, AO);
    } else {
        hipLaunchKernelGGL(k_attn, dim3((N_/128) * 32), dim3(256), 0, stream, Qn, Kn, Vt, AO);
    }
    hipLaunchKernelGGL(k_proj, dim3(C_/64, N_/64, B_), dim3(256), 0, stream, wob, b_out, AO, out);
}